// Round 3
// baseline (5438.645 us; speedup 1.0000x reference)
//
#include <hip/hip_runtime.h>
#include <float.h>
#include <math.h>

namespace {

constexpr int BB = 4;
constexpr int NP = 2048;
constexpr int KK = 20;
constexpr float NEGS = 0.2f;
constexpr float BEPS = 1e-5f;

__device__ inline float wmax(float v){
  #pragma unroll
  for(int m=32;m>=1;m>>=1) v = fmaxf(v, __shfl_xor(v, m, 64));
  return v;
}
__device__ inline float wsum(float v){
  #pragma unroll
  for(int m=32;m>=1;m>>=1) v += __shfl_xor(v, m, 64);
  return v;
}

__global__ void k_meanx(const float* __restrict__ x, float* __restrict__ meanx){
  int bc = blockIdx.x;
  const float* p = x + (size_t)bc*NP;
  float s=0.f;
  for(int n=threadIdx.x;n<NP;n+=256) s+=p[n];
  __shared__ float red[256];
  red[threadIdx.x]=s; __syncthreads();
  for(int st=128;st>0;st>>=1){ if(threadIdx.x<st) red[threadIdx.x]+=red[threadIdx.x+st]; __syncthreads(); }
  if(threadIdx.x==0) meanx[bc]=red[0]/(float)NP;
}

__global__ void k_repsurf(const float* __restrict__ x, const float* __restrict__ meanx, float* __restrict__ f){
  int t=blockIdx.x*256+threadIdx.x;
  if(t>=BB*NP) return;
  int b=t/NP, n=t%NP;
  float p0=x[(b*3+0)*NP+n], p1=x[(b*3+1)*NP+n], p2=x[(b*3+2)*NP+n];
  float c0=p0-meanx[b*3+0], c1=p1-meanx[b*3+1], c2=p2-meanx[b*3+2];
  float r=sqrtf(p0*p0+p1*p1+p2*p2);
  float* fb=f+(size_t)b*10*NP+n;
  fb[0]=p0; fb[NP]=p1; fb[2*NP]=p2;
  fb[3*NP]=c0; fb[4*NP]=c1; fb[5*NP]=c2;
  fb[6*NP]=p0*p0; fb[7*NP]=p1*p1; fb[8*NP]=p2*p2;
  fb[9*NP]=r;
}

// out[s*R + r] = in[r*rs + off + s]
__global__ void k_transpose(const float* __restrict__ in, float* __restrict__ out, int R, int S, int rs, int off){
  int t=blockIdx.x*256+threadIdx.x;
  if(t>=R*S) return;
  int s=t/R, r=t%R;
  out[(size_t)s*R+r] = in[(size_t)r*rs + off + s];
}

__global__ void k_sqnorm(const float* __restrict__ x, size_t BS, float* __restrict__ sq, int C){
  int t=blockIdx.x*256+threadIdx.x;
  if(t>=BB*NP)return;
  int b=t/NP, n=t%NP;
  const float* xb=x+(size_t)b*BS+n;
  float s=0.f;
  for(int c=0;c<C;c++){ float v=xb[(size_t)c*NP]; s+=v*v; }
  sq[t]=s;
}

__global__ void k_xT(const float* __restrict__ x, size_t BS, float* __restrict__ xT, int C){
  int t=blockIdx.x*256+threadIdx.x;
  if(t>=BB*NP*C) return;
  int c=t%C; int n=(t/C)%NP; int b=t/(C*NP);
  xT[t] = x[(size_t)b*BS + (size_t)c*NP + n];
}

__global__ __launch_bounds__(256) void k_dist(const float* __restrict__ xb, const float* __restrict__ sqb,
                                              float* __restrict__ D, int C){
  __shared__ __align__(16) float At[16][64];
  __shared__ __align__(16) float Bt[16][64];
  int j0 = blockIdx.x*64, i0 = blockIdx.y*64;
  int tx = threadIdx.x%16, ty = threadIdx.x/16;
  float acc[4][4];
  #pragma unroll
  for(int a=0;a<4;a++)
    #pragma unroll
    for(int bq=0;bq<4;bq++) acc[a][bq]=0.f;
  for(int c0=0;c0<C;c0+=16){
    #pragma unroll
    for(int r=0;r<4;r++){
      int tl = threadIdx.x + 256*r;
      int c = tl/64, e = tl%64;
      int cg = c0+c;
      At[c][e] = (cg<C)? xb[(size_t)cg*NP + i0 + e] : 0.f;
      Bt[c][e] = (cg<C)? xb[(size_t)cg*NP + j0 + e] : 0.f;
    }
    __syncthreads();
    int cm = (C-c0 < 16)? (C-c0) : 16;
    for(int c=0;c<cm;c++){
      float4 a4=*(const float4*)&At[c][ty*4];
      float4 b4=*(const float4*)&Bt[c][tx*4];
      float ar[4]={a4.x,a4.y,a4.z,a4.w}, br[4]={b4.x,b4.y,b4.z,b4.w};
      #pragma unroll
      for(int ii=0;ii<4;ii++)
        #pragma unroll
        for(int jj=0;jj<4;jj++) acc[ii][jj] += ar[ii]*br[jj];
    }
    __syncthreads();
  }
  #pragma unroll
  for(int ii=0;ii<4;ii++){
    int i=i0+ty*4+ii;
    float si=sqb[i];
    #pragma unroll
    for(int jj=0;jj<4;jj++){
      int j=j0+tx*4+jj;
      D[(size_t)i*NP + j] = si + sqb[j] - 2.f*acc[ii][jj];
    }
  }
}

__global__ __launch_bounds__(256) void k_topk(const float* __restrict__ D, int* __restrict__ out){
  int wid = threadIdx.x>>6, lane = threadIdx.x&63;
  int row = blockIdx.x*4 + wid;
  const float* d = D + (size_t)row*NP;
  unsigned long long r[20];
  #pragma unroll
  for(int q=0;q<20;q++) r[q]=~0ULL;
  for(int t=0;t<NP/64;t++){
    int j = lane + 64*t;
    float v = d[j];
    unsigned u = __float_as_uint(v);
    u = (u & 0x80000000u) ? ~u : (u | 0x80000000u);
    unsigned long long key = ((unsigned long long)u<<32) | (unsigned)j;
    #pragma unroll
    for(int q=0;q<20;q++){
      unsigned long long lo = key<r[q]?key:r[q];
      unsigned long long hi = key<r[q]?r[q]:key;
      r[q]=lo; key=hi;
    }
  }
  int* o = out + (size_t)row*KK;
  for(int kk=0;kk<KK;kk++){
    unsigned long long m = r[0];
    #pragma unroll
    for(int off=1;off<64;off<<=1){
      unsigned long long ot = __shfl_xor(m, off, 64);
      if(ot<m) m=ot;
    }
    if(lane==0) o[kk] = (int)(unsigned)(m & 0xffffffffULL);
    if(r[0]==m){
      #pragma unroll
      for(int q=0;q<19;q++) r[q]=r[q+1];
      r[19]=~0ULL;
    }
  }
}

__global__ void k_nbmax(const float* __restrict__ x, size_t BS, const int* __restrict__ idx,
                        float* __restrict__ nbm, int C){
  int t=blockIdx.x*256+threadIdx.x;
  if(t>=BB*C*NP)return;
  int n=t%NP; int bc=t/NP; int c=bc%C; int b=bc/C;
  const int* id=idx+((size_t)b*NP+n)*KK;
  const float* xr=x+(size_t)b*BS+(size_t)c*NP;
  float m=-FLT_MAX;
  for(int k=0;k<KK;k++) m=fmaxf(m,xr[id[k]]);
  nbm[t]=m;
}

template<bool RELU, bool BIAS>
__global__ __launch_bounds__(256) void k_gemm(
    const float* __restrict__ WT, int O, int Cin,
    const float* __restrict__ p1, size_t bs1, int split,
    const float* __restrict__ p2, size_t bs2,
    const float* __restrict__ bias,
    float* __restrict__ out, size_t obs){
  __shared__ __align__(16) float At[16][64];
  __shared__ __align__(16) float Bt[16][64];
  int n0=blockIdx.x*64, o0=blockIdx.y*64, b=blockIdx.z;
  int tx=threadIdx.x%16, ty=threadIdx.x/16;
  float acc[4][4];
  #pragma unroll
  for(int a=0;a<4;a++)
    #pragma unroll
    for(int bq=0;bq<4;bq++) acc[a][bq]=0.f;
  for(int c0=0;c0<Cin;c0+=16){
    #pragma unroll
    for(int r=0;r<4;r++){
      int tl=threadIdx.x+256*r;
      int c=tl/64, e=tl%64;
      int cg=c0+c;
      At[c][e] = (cg<Cin && o0+e<O)? WT[(size_t)cg*O + o0+e] : 0.f;
      float bv=0.f;
      if(cg<Cin){
        bv = (cg<split)? p1[(size_t)b*bs1 + (size_t)cg*NP + n0+e]
                       : p2[(size_t)b*bs2 + (size_t)(cg-split)*NP + n0+e];
      }
      Bt[c][e]=bv;
    }
    __syncthreads();
    int cm = (Cin-c0 < 16)? (Cin-c0) : 16;
    for(int c=0;c<cm;c++){
      float4 a4=*(const float4*)&At[c][ty*4];
      float4 b4=*(const float4*)&Bt[c][tx*4];
      float ar[4]={a4.x,a4.y,a4.z,a4.w}, br[4]={b4.x,b4.y,b4.z,b4.w};
      #pragma unroll
      for(int ii=0;ii<4;ii++)
        #pragma unroll
        for(int jj=0;jj<4;jj++) acc[ii][jj] += ar[ii]*br[jj];
    }
    __syncthreads();
  }
  #pragma unroll
  for(int ii=0;ii<4;ii++){
    int oo=o0+ty*4+ii;
    if(oo<O){
      float bia = BIAS? bias[(size_t)b*O+oo] : 0.f;
      #pragma unroll
      for(int jj=0;jj<4;jj++){
        int n=n0+tx*4+jj;
        float v=acc[ii][jj]+bia;
        if(RELU) v=fmaxf(v,0.f);
        out[(size_t)b*obs + (size_t)oo*NP + n]=v;
      }
    }
  }
}

template<int C, int Cout>
__global__ __launch_bounds__(256) void k_edge2(
    const float* __restrict__ xT, const int* __restrict__ idx,
    const float* __restrict__ wa1T, const float* __restrict__ wa2T,
    const float* __restrict__ wecAT, const float* __restrict__ wecBT,
    const float* __restrict__ gp,
    float* __restrict__ ymaxb, float* __restrict__ yminb,
    float* __restrict__ sumb, float* __restrict__ ssqb){
  constexpr int SE = C+4;
  constexpr int OG = Cout/4, KG = 256/OG, KPT = (KK+KG-1)/KG;
  __shared__ __align__(16) float ee[KK][SE];
  __shared__ __align__(16) float aa[KK][SE];
  __shared__ float xi[C], t2s[C], t3s[Cout];
  __shared__ float rmx[KG*Cout], rmn[KG*Cout], rsm[KG*Cout], rss[KG*Cout];
  __shared__ int sid[KK];
  int b = blockIdx.x/NP, n = blockIdx.x%NP;
  int tid = threadIdx.x;
  const float* xrow = xT + ((size_t)b*NP + n)*C;
  if(tid<C) xi[tid]=xrow[tid];
  if(tid>=C && tid<C+KK) sid[tid-C]=idx[((size_t)b*NP+n)*KK + (tid-C)];
  __syncthreads();
  if(tid<C){
    float s=0.f;
    for(int c=0;c<C;c++) s += wa2T[c*C+tid]*xi[c];
    t2s[tid]=s;
  }
  if(tid<Cout){
    float s = gp[((size_t)b*Cout+tid)*NP + n];
    for(int c=0;c<C;c++) s += wecBT[c*Cout+tid]*xi[c];
    t3s[tid]=s;
  }
  for(int t=tid;t<KK*C;t+=256){
    int k=t/C, c=t-k*C;
    ee[k][c] = xT[((size_t)b*NP + sid[k])*C + c] - xi[c];
  }
  __syncthreads();
  if constexpr (C==10){
    if(tid < C*KK){
      int o = tid%C, k = tid/C;
      float s = t2s[o];
      for(int c=0;c<C;c++) s += wa1T[c*C+o]*ee[k][c];
      aa[k][o] = s>0.f? s : NEGS*s;
    }
  } else {
    constexpr int OG2=C/4, KG2=256/OG2, KPT2=(KK+KG2-1)/KG2;
    int og2 = tid%OG2, kg2 = tid/OG2, ob = og2*4;
    float acc2[KPT2][4];
    #pragma unroll
    for(int t=0;t<KPT2;t++)
      #pragma unroll
      for(int j=0;j<4;j++) acc2[t][j]=t2s[ob+j];
    for(int c=0;c<C;c+=4){
      float4 w0=*(const float4*)&wa1T[(c+0)*C+ob];
      float4 w1=*(const float4*)&wa1T[(c+1)*C+ob];
      float4 w2=*(const float4*)&wa1T[(c+2)*C+ob];
      float4 w3=*(const float4*)&wa1T[(c+3)*C+ob];
      #pragma unroll
      for(int t=0;t<KPT2;t++){
        int k = kg2 + KG2*t;
        if(k<KK){
          float4 e4 = *(const float4*)&ee[k][c];
          acc2[t][0] += w0.x*e4.x + w1.x*e4.y + w2.x*e4.z + w3.x*e4.w;
          acc2[t][1] += w0.y*e4.x + w1.y*e4.y + w2.y*e4.z + w3.y*e4.w;
          acc2[t][2] += w0.z*e4.x + w1.z*e4.y + w2.z*e4.z + w3.z*e4.w;
          acc2[t][3] += w0.w*e4.x + w1.w*e4.y + w2.w*e4.z + w3.w*e4.w;
        }
      }
    }
    #pragma unroll
    for(int t=0;t<KPT2;t++){
      int k = kg2 + KG2*t;
      if(k<KK){
        float4 lv;
        lv.x = acc2[t][0]>0.f? acc2[t][0] : NEGS*acc2[t][0];
        lv.y = acc2[t][1]>0.f? acc2[t][1] : NEGS*acc2[t][1];
        lv.z = acc2[t][2]>0.f? acc2[t][2] : NEGS*acc2[t][2];
        lv.w = acc2[t][3]>0.f? acc2[t][3] : NEGS*acc2[t][3];
        *(float4*)&aa[k][ob] = lv;
      }
    }
  }
  __syncthreads();
  {
    int wv=tid>>6, lane=tid&63;
    for(int k=wv;k<KK;k+=4){
      if constexpr (C<=64){
        float a = lane<C ? aa[k][lane] : -FLT_MAX;
        float mx=wmax(a);
        float p = lane<C ? __expf(a-mx) : 0.f;
        float sm=wsum(p);
        if(lane<C) ee[k][lane] *= (p/sm);
      } else {
        float a0=aa[k][lane], a1=aa[k][lane+64];
        float mx=wmax(fmaxf(a0,a1));
        float p0=__expf(a0-mx), p1=__expf(a1-mx);
        float sm=wsum(p0+p1);
        ee[k][lane]    *= (p0/sm);
        ee[k][lane+64] *= (p1/sm);
      }
    }
  }
  __syncthreads();
  {
    int og=tid%OG, kg=tid/OG, ob=og*4;
    float acc[KPT][4];
    #pragma unroll
    for(int t=0;t<KPT;t++)
      #pragma unroll
      for(int j=0;j<4;j++) acc[t][j]=0.f;
    if constexpr (C==10){
      for(int c=0;c<C;c++){
        float4 w=*(const float4*)&wecAT[c*Cout+ob];
        float wr[4]={w.x,w.y,w.z,w.w};
        #pragma unroll
        for(int t=0;t<KPT;t++){
          int k=kg+KG*t;
          if(k<KK){
            float e=ee[k][c];
            #pragma unroll
            for(int j=0;j<4;j++) acc[t][j]+=wr[j]*e;
          }
        }
      }
    } else {
      for(int c=0;c<C;c+=4){
        float4 w0=*(const float4*)&wecAT[(c+0)*Cout+ob];
        float4 w1=*(const float4*)&wecAT[(c+1)*Cout+ob];
        float4 w2=*(const float4*)&wecAT[(c+2)*Cout+ob];
        float4 w3=*(const float4*)&wecAT[(c+3)*Cout+ob];
        #pragma unroll
        for(int t=0;t<KPT;t++){
          int k=kg+KG*t;
          if(k<KK){
            float4 e4=*(const float4*)&ee[k][c];
            acc[t][0] += w0.x*e4.x + w1.x*e4.y + w2.x*e4.z + w3.x*e4.w;
            acc[t][1] += w0.y*e4.x + w1.y*e4.y + w2.y*e4.z + w3.y*e4.w;
            acc[t][2] += w0.z*e4.x + w1.z*e4.y + w2.z*e4.z + w3.z*e4.w;
            acc[t][3] += w0.w*e4.x + w1.w*e4.y + w2.w*e4.z + w3.w*e4.w;
          }
        }
      }
    }
    float mx[4],mn[4],sm[4],ss[4];
    #pragma unroll
    for(int j=0;j<4;j++){ mx[j]=-FLT_MAX; mn[j]=FLT_MAX; sm[j]=0.f; ss[j]=0.f; }
    #pragma unroll
    for(int t=0;t<KPT;t++){
      int k=kg+KG*t;
      if(k<KK){
        #pragma unroll
        for(int j=0;j<4;j++){
          float y=acc[t][j]+t3s[ob+j];
          mx[j]=fmaxf(mx[j],y); mn[j]=fminf(mn[j],y); sm[j]+=y; ss[j]+=y*y;
        }
      }
    }
    #pragma unroll
    for(int j=0;j<4;j++){
      rmx[kg*Cout+ob+j]=mx[j];
      rmn[kg*Cout+ob+j]=mn[j];
      rsm[kg*Cout+ob+j]=sm[j];
      rss[kg*Cout+ob+j]=ss[j];
    }
    __syncthreads();
    if(kg==0){
      for(int g=1;g<KG;g++){
        #pragma unroll
        for(int j=0;j<4;j++){
          mx[j]=fmaxf(mx[j],rmx[g*Cout+ob+j]);
          mn[j]=fminf(mn[j],rmn[g*Cout+ob+j]);
          sm[j]+=rsm[g*Cout+ob+j];
          ss[j]+=rss[g*Cout+ob+j];
        }
      }
      #pragma unroll
      for(int j=0;j<4;j++){
        ymaxb[((size_t)b*Cout+ob+j)*NP+n]=mx[j];
        yminb[((size_t)b*Cout+ob+j)*NP+n]=mn[j];
        atomicAdd(&sumb[ob+j],sm[j]);
        atomicAdd(&ssqb[ob+j],ss[j]);
      }
    }
  }
}

__global__ void k_bnprep(const float* __restrict__ sumb, const float* __restrict__ ssqb,
                         const float* __restrict__ gg, const float* __restrict__ bb,
                         float* __restrict__ sct, int Cout, float invcnt){
  int o=blockIdx.x*256+threadIdx.x;
  if(o>=Cout)return;
  float m=sumb[o]*invcnt;
  float v=ssqb[o]*invcnt-m*m;
  float s=gg[o]*rsqrtf(v+BEPS);
  sct[o]=s; sct[Cout+o]=bb[o]-s*m;
}

__global__ void k_stageout(const float* __restrict__ ymaxb, const float* __restrict__ yminb,
                           const float* __restrict__ sct, float* __restrict__ xo, int Cout, size_t obs){
  int t=blockIdx.x*256+threadIdx.x;
  if(t>=BB*Cout*NP)return;
  int n=t%NP; int r=t/NP; int o=r%Cout; int b=r/Cout;
  float s=sct[o], tt=sct[Cout+o];
  float y = s>=0.f ? fmaf(s,ymaxb[t],tt) : fmaf(s,yminb[t],tt);
  xo[(size_t)b*obs + (size_t)o*NP + n]=fmaxf(y,0.f);
}

__global__ void k_stats(const float* __restrict__ y, const float* __restrict__ gg, const float* __restrict__ bb,
                        float* __restrict__ sct, int Cch){
  int o=blockIdx.x;
  float s=0.f, ss=0.f;
  for(int t=threadIdx.x;t<BB*NP;t+=256){
    int b=t/NP, n=t%NP;
    float v=y[((size_t)b*Cch+o)*NP+n];
    s+=v; ss+=v*v;
  }
  __shared__ float r1[256], r2[256];
  r1[threadIdx.x]=s; r2[threadIdx.x]=ss;
  __syncthreads();
  for(int st=128;st>0;st>>=1){
    if(threadIdx.x<st){ r1[threadIdx.x]+=r1[threadIdx.x+st]; r2[threadIdx.x]+=r2[threadIdx.x+st]; }
    __syncthreads();
  }
  if(threadIdx.x==0){
    float m=r1[0]/(float)(BB*NP);
    float v=r2[0]/(float)(BB*NP)-m*m;
    float sc=gg[o]*rsqrtf(v+BEPS);
    sct[o]=sc; sct[Cch+o]=bb[o]-sc*m;
  }
}

__global__ void k_gvec(const float* __restrict__ y5, const float* __restrict__ sct, float* __restrict__ gvec){
  int bo=blockIdx.x; int b=bo>>10, o=bo&1023;
  float sc=sct[o], sh=sct[1024+o];
  float m=-FLT_MAX;
  for(int n=threadIdx.x;n<NP;n+=256) m=fmaxf(m, fmaf(sc,y5[((size_t)b*1024+o)*NP+n],sh));
  __shared__ float r[256];
  r[threadIdx.x]=m; __syncthreads();
  for(int st=128;st>0;st>>=1){ if(threadIdx.x<st) r[threadIdx.x]=fmaxf(r[threadIdx.x],r[threadIdx.x+st]); __syncthreads(); }
  if(threadIdx.x==0) gvec[bo]=fmaxf(r[0],0.f);
}

__global__ void k_t6(const float* __restrict__ gvec, const float* __restrict__ w6, float* __restrict__ t6b){
  int t=blockIdx.x*256+threadIdx.x;
  if(t>=BB*512)return;
  int b=t/512, o=t%512;
  const float* w=w6+(size_t)o*1152+128;
  const float* gv=gvec+(size_t)b*1024;
  float s=0.f;
  for(int c=0;c<1024;c++) s+=w[c]*gv[c];
  t6b[t]=s;
}

__global__ void k_norm(float* __restrict__ y, const float* __restrict__ sct, int Cch, int total){
  int t=blockIdx.x*256+threadIdx.x;
  if(t>=total)return;
  int o=(t/NP)%Cch;
  y[t]=fmaxf(fmaf(sct[o],y[t],sct[Cch+o]),0.f);
}

} // namespace

extern "C" void kernel_launch(void* const* d_in, const int* in_sizes, int n_in,
                              void* d_out, int out_size, void* d_ws, size_t ws_size,
                              hipStream_t stream){
  const float* x   =(const float*)d_in[0];
  const float* wa_1[4]={(const float*)d_in[1],(const float*)d_in[3],(const float*)d_in[5],(const float*)d_in[7]};
  const float* wa_2[4]={(const float*)d_in[2],(const float*)d_in[4],(const float*)d_in[6],(const float*)d_in[8]};
  const float* wfn[4]={(const float*)d_in[9],(const float*)d_in[10],(const float*)d_in[11],(const float*)d_in[12]};
  const float* wec[4]={(const float*)d_in[13],(const float*)d_in[14],(const float*)d_in[15],(const float*)d_in[16]};
  const float* w5=(const float*)d_in[17];
  const float* w6=(const float*)d_in[18];
  const float* w7=(const float*)d_in[19];
  const float* w8=(const float*)d_in[20];
  const float* gs[7]; const float* bs[7];
  for(int i=0;i<7;i++){ gs[i]=(const float*)d_in[21+2*i]; bs[i]=(const float*)d_in[22+2*i]; }

  const int Cs[4]={10,64,64,128};
  const int Co[4]={64,64,128,256};
  const size_t U=(size_t)BB*NP;

  float* base=(float*)d_ws;
  size_t off=0;
  auto alloc=[&](size_t nfl)->float*{ float* p=base+off; off+=(nfl+3)&~(size_t)3; return p; };

  float* f_buf = alloc(10*U);
  float* xcat  = alloc(512*U);
  float* sq    = alloc(U);
  int*   idxb  = (int*)alloc(20*U);
  float* xTb   = alloc(128*U);
  float* REG   = alloc(1536*U);
  float* Dbuf  = REG;
  float* nbm   = REG;
  float* gfb   = REG + 128*U;
  float* gpb   = REG + 640*U;
  float* ymx   = REG + 896*U;
  float* ymn   = REG + 1152*U;
  float* y5    = REG;
  float* y6    = REG + 1024*U;
  float* y7    = REG;
  float* sums  = alloc(2048);
  float* sct   = alloc(2048);
  float* gvecb = alloc(BB*1024);
  float* t6b   = alloc(BB*512);
  float* meanxb= alloc(16);
  float* wa1T[4]; float* wa2T[4]; float* wecAT[4]; float* wecBT[4]; float* wecGT[4]; float* wfnT[4];
  for(int s=0;s<4;s++){
    int C=Cs[s], Cout=Co[s];
    wa1T[s]=alloc((size_t)C*C); wa2T[s]=alloc((size_t)C*C);
    wecAT[s]=alloc((size_t)C*Cout); wecBT[s]=alloc((size_t)C*Cout);
    wecGT[s]=alloc((size_t)512*Cout); wfnT[s]=alloc((size_t)2*C*512);
  }
  float* w5T=alloc((size_t)512*1024); float* w6mT=alloc((size_t)128*512);
  float* w7T=alloc((size_t)512*256);  float* w8T=alloc((size_t)256*50);
  (void)ws_size;

  hipMemsetAsync(sums,0,2048*sizeof(float),stream);

  for(int s=0;s<4;s++){
    int C=Cs[s], Cout=Co[s], Cin=2*C+512;
    k_transpose<<<(C*C+255)/256,256,0,stream>>>(wa_1[s],wa1T[s],C,C,C,0);
    k_transpose<<<(C*C+255)/256,256,0,stream>>>(wa_2[s],wa2T[s],C,C,C,0);
    k_transpose<<<(C*Cout+255)/256,256,0,stream>>>(wec[s],wecAT[s],Cout,C,Cin,0);
    k_transpose<<<(C*Cout+255)/256,256,0,stream>>>(wec[s],wecBT[s],Cout,C,Cin,C);
    k_transpose<<<(512*Cout+255)/256,256,0,stream>>>(wec[s],wecGT[s],Cout,512,Cin,2*C);
    k_transpose<<<(2*C*512+255)/256,256,0,stream>>>(wfn[s],wfnT[s],512,2*C,2*C,0);
  }
  k_transpose<<<(512*1024+255)/256,256,0,stream>>>(w5,w5T,1024,512,512,0);
  k_transpose<<<(128*512+255)/256,256,0,stream>>>(w6,w6mT,512,128,1152,0);
  k_transpose<<<(512*256+255)/256,256,0,stream>>>(w7,w7T,256,512,512,0);
  k_transpose<<<(256*50+255)/256,256,0,stream>>>(w8,w8T,50,256,256,0);

  k_meanx<<<12,256,0,stream>>>(x,meanxb);
  k_repsurf<<<(BB*NP+255)/256,256,0,stream>>>(x,meanxb,f_buf);

  const float* xin[4]={f_buf, xcat, xcat+(size_t)64*NP, xcat+(size_t)128*NP};
  const size_t BSs[4]={(size_t)10*NP,(size_t)512*NP,(size_t)512*NP,(size_t)512*NP};
  float* xoutb[4]={xcat, xcat+(size_t)64*NP, xcat+(size_t)128*NP, xcat+(size_t)256*NP};

  for(int s=0;s<4;s++){
    int C=Cs[s], Cout=Co[s];
    size_t BS=BSs[s];
    k_sqnorm<<<(BB*NP+255)/256,256,0,stream>>>(xin[s],BS,sq,C);
    for(int b=0;b<BB;b++){
      k_dist<<<dim3(32,32),256,0,stream>>>(xin[s]+(size_t)b*BS, sq+(size_t)b*NP, Dbuf, C);
      k_topk<<<NP/4,256,0,stream>>>(Dbuf, idxb+(size_t)b*NP*KK);
    }
    k_xT<<<(BB*NP*C+255)/256,256,0,stream>>>(xin[s],BS,xTb,C);
    k_nbmax<<<(BB*C*NP+255)/256,256,0,stream>>>(xin[s],BS,idxb,nbm,C);
    k_gemm<true,false><<<dim3(32,8,BB),256,0,stream>>>(wfnT[s],512,2*C, xin[s],BS,C, nbm,(size_t)C*NP,
                                                       nullptr, gfb,(size_t)512*NP);
    k_gemm<false,false><<<dim3(32,(Cout+63)/64,BB),256,0,stream>>>(wecGT[s],Cout,512, gfb,(size_t)512*NP,512,
                                                       nullptr,0, nullptr, gpb,(size_t)Cout*NP);
    float* sb=sums+(size_t)s*512; float* qb=sb+256;
    if(s==0)      k_edge2<10,64  ><<<BB*NP,256,0,stream>>>(xTb,idxb,wa1T[s],wa2T[s],wecAT[s],wecBT[s],gpb,ymx,ymn,sb,qb);
    else if(s==1) k_edge2<64,64  ><<<BB*NP,256,0,stream>>>(xTb,idxb,wa1T[s],wa2T[s],wecAT[s],wecBT[s],gpb,ymx,ymn,sb,qb);
    else if(s==2) k_edge2<64,128 ><<<BB*NP,256,0,stream>>>(xTb,idxb,wa1T[s],wa2T[s],wecAT[s],wecBT[s],gpb,ymx,ymn,sb,qb);
    else          k_edge2<128,256><<<BB*NP,256,0,stream>>>(xTb,idxb,wa1T[s],wa2T[s],wecAT[s],wecBT[s],gpb,ymx,ymn,sb,qb);
    k_bnprep<<<1,256,0,stream>>>(sb,qb,gs[s],bs[s],sct,Cout,1.f/(float)((size_t)BB*NP*KK));
    k_stageout<<<(BB*Cout*NP+255)/256,256,0,stream>>>(ymx,ymn,sct,xoutb[s],Cout,(size_t)512*NP);
  }

  k_gemm<false,false><<<dim3(32,16,BB),256,0,stream>>>(w5T,1024,512, xcat,(size_t)512*NP,512,
                                                       nullptr,0, nullptr, y5,(size_t)1024*NP);
  k_stats<<<1024,256,0,stream>>>(y5,gs[4],bs[4],sct,1024);
  k_gvec<<<BB*1024,256,0,stream>>>(y5,sct,gvecb);
  k_t6<<<(BB*512+255)/256,256,0,stream>>>(gvecb,w6,t6b);
  k_gemm<false,true><<<dim3(32,8,BB),256,0,stream>>>(w6mT,512,128, xcat+(size_t)128*NP,(size_t)512*NP,128,
                                                       nullptr,0, t6b, y6,(size_t)512*NP);
  k_stats<<<512,256,0,stream>>>(y6,gs[5],bs[5],sct,512);
  k_norm<<<((int)(BB*512*NP)+255)/256,256,0,stream>>>(y6,sct,512,(int)(BB*512*NP));
  k_gemm<false,false><<<dim3(32,4,BB),256,0,stream>>>(w7T,256,512, y6,(size_t)512*NP,512,
                                                       nullptr,0, nullptr, y7,(size_t)256*NP);
  k_stats<<<256,256,0,stream>>>(y7,gs[6],bs[6],sct,256);
  k_norm<<<((int)(BB*256*NP)+255)/256,256,0,stream>>>(y7,sct,256,(int)(BB*256*NP));
  k_gemm<true,false><<<dim3(32,1,BB),256,0,stream>>>(w8T,50,256, y7,(size_t)256*NP,256,
                                                       nullptr,0, nullptr, (float*)d_out,(size_t)50*NP);

  (void)in_sizes; (void)n_in; (void)out_size;
}

// Round 4
// 4424.811 us; speedup vs baseline: 1.2291x; 1.2291x over previous
//
#include <hip/hip_runtime.h>
#include <float.h>
#include <math.h>

namespace {

constexpr int BB = 4;
constexpr int NP = 2048;
constexpr int KK = 20;
constexpr int KN = KK*NP;          // 40960
constexpr float NEGS = 0.2f;
constexpr float BEPS = 1e-5f;

__global__ void k_meanx(const float* __restrict__ x, float* __restrict__ meanx){
  int bc = blockIdx.x;
  const float* p = x + (size_t)bc*NP;
  float s=0.f;
  for(int n=threadIdx.x;n<NP;n+=256) s+=p[n];
  __shared__ float red[256];
  red[threadIdx.x]=s; __syncthreads();
  for(int st=128;st>0;st>>=1){ if(threadIdx.x<st) red[threadIdx.x]+=red[threadIdx.x+st]; __syncthreads(); }
  if(threadIdx.x==0) meanx[bc]=red[0]/(float)NP;
}

__global__ void k_repsurf(const float* __restrict__ x, const float* __restrict__ meanx, float* __restrict__ f){
  int t=blockIdx.x*256+threadIdx.x;
  if(t>=BB*NP) return;
  int b=t/NP, n=t%NP;
  float p0=x[(b*3+0)*NP+n], p1=x[(b*3+1)*NP+n], p2=x[(b*3+2)*NP+n];
  float c0=p0-meanx[b*3+0], c1=p1-meanx[b*3+1], c2=p2-meanx[b*3+2];
  float r=sqrtf(p0*p0+p1*p1+p2*p2);
  float* fb=f+(size_t)b*10*NP+n;
  fb[0]=p0; fb[NP]=p1; fb[2*NP]=p2;
  fb[3*NP]=c0; fb[4*NP]=c1; fb[5*NP]=c2;
  fb[6*NP]=p0*p0; fb[7*NP]=p1*p1; fb[8*NP]=p2*p2;
  fb[9*NP]=r;
}

// out[s*R + r] = in[r*rs + off + s]
__global__ void k_transpose(const float* __restrict__ in, float* __restrict__ out, int R, int S, int rs, int off){
  int t=blockIdx.x*256+threadIdx.x;
  if(t>=R*S) return;
  int s=t/R, r=t%R;
  out[(size_t)s*R+r] = in[(size_t)r*rs + off + s];
}

__global__ void k_sqnorm(const float* __restrict__ x, size_t BS, float* __restrict__ sq, int C){
  int t=blockIdx.x*256+threadIdx.x;
  if(t>=BB*NP)return;
  int b=t/NP, n=t%NP;
  const float* xb=x+(size_t)b*BS+n;
  float s=0.f;
  for(int c=0;c<C;c++){ float v=xb[(size_t)c*NP]; s+=v*v; }
  sq[t]=s;
}

__global__ __launch_bounds__(256) void k_dist(const float* __restrict__ xb, const float* __restrict__ sqb,
                                              float* __restrict__ D, int C){
  __shared__ __align__(16) float At[16][64];
  __shared__ __align__(16) float Bt[16][64];
  int j0 = blockIdx.x*64, i0 = blockIdx.y*64;
  int tx = threadIdx.x%16, ty = threadIdx.x/16;
  float acc[4][4]={};
  for(int c0=0;c0<C;c0+=16){
    #pragma unroll
    for(int r=0;r<4;r++){
      int tl = threadIdx.x + 256*r;
      int c = tl/64, e = tl%64;
      int cg = c0+c;
      At[c][e] = (cg<C)? xb[(size_t)cg*NP + i0 + e] : 0.f;
      Bt[c][e] = (cg<C)? xb[(size_t)cg*NP + j0 + e] : 0.f;
    }
    __syncthreads();
    int cm = (C-c0 < 16)? (C-c0) : 16;
    for(int c=0;c<cm;c++){
      float4 a4=*(const float4*)&At[c][ty*4];
      float4 b4=*(const float4*)&Bt[c][tx*4];
      float ar[4]={a4.x,a4.y,a4.z,a4.w}, br[4]={b4.x,b4.y,b4.z,b4.w};
      #pragma unroll
      for(int ii=0;ii<4;ii++)
        #pragma unroll
        for(int jj=0;jj<4;jj++) acc[ii][jj] += ar[ii]*br[jj];
    }
    __syncthreads();
  }
  #pragma unroll
  for(int ii=0;ii<4;ii++){
    int i=i0+ty*4+ii;
    float si=sqb[i];
    #pragma unroll
    for(int jj=0;jj<4;jj++){
      int j=j0+tx*4+jj;
      D[(size_t)i*NP + j] = si + sqb[j] - 2.f*acc[ii][jj];
    }
  }
}

__global__ __launch_bounds__(256) void k_topk(const float* __restrict__ D, int* __restrict__ out){
  int wid = threadIdx.x>>6, lane = threadIdx.x&63;
  int row = blockIdx.x*4 + wid;
  const float* d = D + (size_t)row*NP;
  unsigned long long r[20];
  #pragma unroll
  for(int q=0;q<20;q++) r[q]=~0ULL;
  for(int t=0;t<NP/64;t++){
    int j = lane + 64*t;
    float v = d[j];
    unsigned u = __float_as_uint(v);
    u = (u & 0x80000000u) ? ~u : (u | 0x80000000u);
    unsigned long long key = ((unsigned long long)u<<32) | (unsigned)j;
    #pragma unroll
    for(int q=0;q<20;q++){
      unsigned long long lo = key<r[q]?key:r[q];
      unsigned long long hi = key<r[q]?r[q]:key;
      r[q]=lo; key=hi;
    }
  }
  int* o = out + (size_t)row*KK;
  for(int kk=0;kk<KK;kk++){
    unsigned long long m = r[0];
    #pragma unroll
    for(int off=1;off<64;off<<=1){
      unsigned long long ot = __shfl_xor(m, off, 64);
      if(ot<m) m=ot;
    }
    if(lane==0) o[kk] = (int)(unsigned)(m & 0xffffffffULL);
    if(r[0]==m){
      #pragma unroll
      for(int q=0;q<19;q++) r[q]=r[q+1];
      r[19]=~0ULL;
    }
  }
}

__global__ void k_nbmax(const float* __restrict__ x, size_t BS, const int* __restrict__ idx,
                        float* __restrict__ nbm, int C){
  int t=blockIdx.x*256+threadIdx.x;
  if(t>=BB*C*NP)return;
  int n=t%NP; int bc=t/NP; int c=bc%C; int b=bc/C;
  const int* id=idx+((size_t)b*NP+n)*KK;
  const float* xr=x+(size_t)b*BS+(size_t)c*NP;
  float m=-FLT_MAX;
  for(int k=0;k<KK;k++) m=fmaxf(m,xr[id[k]]);
  nbm[t]=m;
}

// generic tiled GEMM: out[b][o][col] = WT^T @ B (+epilogue), B rows of length ncols.
// EPI: 0 none, 1 relu, 2 add tensor (same layout as out), 3 bias per (b,o)
template<int EPI>
__global__ __launch_bounds__(256) void k_gemm(
    const float* __restrict__ WT, int Os, int O, int Cin,
    const float* __restrict__ B1, size_t bs1, int split,
    const float* __restrict__ B2, size_t bs2,
    const float* __restrict__ ADD, size_t abs_,
    float* __restrict__ out, size_t obs, int ncols){
  __shared__ __align__(16) float At[16][64];
  __shared__ __align__(16) float Bt[16][64];
  int n0=blockIdx.x*64, o0=blockIdx.y*64, b=blockIdx.z;
  int tx=threadIdx.x%16, ty=threadIdx.x/16;
  float acc[4][4]={};
  for(int c0=0;c0<Cin;c0+=16){
    #pragma unroll
    for(int r=0;r<4;r++){
      int tl=threadIdx.x+256*r;
      int c=tl/64, e=tl%64;
      int cg=c0+c;
      At[c][e] = (cg<Cin && o0+e<O)? WT[(size_t)cg*Os + o0+e] : 0.f;
      float bv=0.f;
      if(cg<Cin){
        bv = (cg<split)? B1[(size_t)b*bs1 + (size_t)cg*ncols + n0+e]
                       : B2[(size_t)b*bs2 + (size_t)(cg-split)*ncols + n0+e];
      }
      Bt[c][e]=bv;
    }
    __syncthreads();
    int cm = (Cin-c0 < 16)? (Cin-c0) : 16;
    for(int c=0;c<cm;c++){
      float4 a4=*(const float4*)&At[c][ty*4];
      float4 b4=*(const float4*)&Bt[c][tx*4];
      float ar[4]={a4.x,a4.y,a4.z,a4.w}, br[4]={b4.x,b4.y,b4.z,b4.w};
      #pragma unroll
      for(int ii=0;ii<4;ii++)
        #pragma unroll
        for(int jj=0;jj<4;jj++) acc[ii][jj] += ar[ii]*br[jj];
    }
    __syncthreads();
  }
  #pragma unroll
  for(int ii=0;ii<4;ii++){
    int oo=o0+ty*4+ii;
    if(oo<O){
      #pragma unroll
      for(int jj=0;jj<4;jj++){
        int col=n0+tx*4+jj;
        float v=acc[ii][jj];
        if constexpr (EPI==2) v += ADD[(size_t)b*abs_ + (size_t)oo*ncols + col];
        if constexpr (EPI==3) v += ADD[(size_t)b*abs_ + oo];
        if constexpr (EPI==1) v = fmaxf(v,0.f);
        out[(size_t)b*obs + (size_t)oo*ncols + col]=v;
      }
    }
  }
}

// A[bz][C][KN] = leaky(Wa1 @ DIFF + T2), DIFF generated during staging via idx gather
template<int C>
__global__ __launch_bounds__(256) void k_gatherA(
    const float* __restrict__ x, size_t BS,
    const int* __restrict__ idx,
    const float* __restrict__ wa1T,
    const float* __restrict__ T2,     // [b][C][NP] full-batch
    float* __restrict__ A, int b0){
  __shared__ __align__(16) float At[16][64];
  __shared__ __align__(16) float Bt[16][64];
  __shared__ int sid[64];
  int j0=blockIdx.x*64, o0=blockIdx.y*64, bz=blockIdx.z, b=b0+bz;
  int tid=threadIdx.x, tx=tid%16, ty=tid/16;
  int kq=j0>>11, nb0=j0&(NP-1);
  if(tid<64){
    int n=nb0+tid;
    sid[tid]=idx[((size_t)b*NP+n)*KK+kq];
  }
  __syncthreads();
  const float* xs=x+(size_t)b*BS;
  float acc[4][4]={};
  for(int c0=0;c0<C;c0+=16){
    #pragma unroll
    for(int r=0;r<4;r++){
      int tl=tid+256*r;
      int c=tl/64, e=tl%64;
      int cg=c0+c;
      At[c][e] = (cg<C && o0+e<C)? wa1T[cg*C + o0+e] : 0.f;
      Bt[c][e] = (cg<C)? xs[(size_t)cg*NP + sid[e]] - xs[(size_t)cg*NP + nb0+e] : 0.f;
    }
    __syncthreads();
    int cm = (C-c0 < 16)? (C-c0) : 16;
    for(int c=0;c<cm;c++){
      float4 a4=*(const float4*)&At[c][ty*4];
      float4 b4=*(const float4*)&Bt[c][tx*4];
      float ar[4]={a4.x,a4.y,a4.z,a4.w}, br[4]={b4.x,b4.y,b4.z,b4.w};
      #pragma unroll
      for(int ii=0;ii<4;ii++)
        #pragma unroll
        for(int jj=0;jj<4;jj++) acc[ii][jj] += ar[ii]*br[jj];
    }
    __syncthreads();
  }
  const float* t2b=T2+(size_t)b*C*NP;
  float* Ab=A+(size_t)bz*(size_t)C*KN;
  #pragma unroll
  for(int ii=0;ii<4;ii++){
    int oo=o0+ty*4+ii;
    if(oo<C){
      #pragma unroll
      for(int jj=0;jj<4;jj++){
        int col=j0+tx*4+jj;
        int n=nb0+tx*4+jj;
        float v=acc[ii][jj]+t2b[(size_t)oo*NP+n];
        v = v>0.f? v : NEGS*v;
        Ab[(size_t)oo*KN+col]=v;
      }
    }
  }
}

// per-column channel softmax, then A <- alpha * diff (in place)
template<int C>
__global__ void k_smscale(float* __restrict__ A, const float* __restrict__ x, size_t BS,
                          const int* __restrict__ idx, int b0){
  int col=blockIdx.x*256+threadIdx.x;
  int bz=blockIdx.z, b=b0+bz;
  int n=col&(NP-1), k=col>>11;
  float* Ab=A+(size_t)bz*(size_t)C*KN+col;
  float m=-FLT_MAX;
  for(int c=0;c<C;c++) m=fmaxf(m,Ab[(size_t)c*KN]);
  float s=0.f;
  for(int c=0;c<C;c++){ float e=__expf(Ab[(size_t)c*KN]-m); Ab[(size_t)c*KN]=e; s+=e; }
  float rs=1.f/s;
  const float* xs=x+(size_t)b*BS;
  int id=idx[((size_t)b*NP+n)*KK+k];
  for(int c=0;c<C;c++){
    Ab[(size_t)c*KN] = Ab[(size_t)c*KN]*rs*(xs[(size_t)c*NP+id]-xs[(size_t)c*NP+n]);
  }
}

// Y = WecA @ EE + T3, fold stats over k inside the block (Y never materialized)
template<int C, int Cout>
__global__ __launch_bounds__(256) void k_yfold(
    const float* __restrict__ EE,     // [bz][C][KN]
    const float* __restrict__ wecAT,  // [C][Cout]
    const float* __restrict__ T3,     // [b][Cout][NP] full-batch
    float* __restrict__ ymx, float* __restrict__ ymn,
    float* __restrict__ sumb, float* __restrict__ ssqb, int b0){
  constexpr int CP=((C+15)/16)*16;
  __shared__ __align__(16) float W[CP][64];
  __shared__ __align__(16) float Bt[16][64];
  int n0=blockIdx.x*64, o0=blockIdx.y*64, bz=blockIdx.z, b=b0+bz;
  int tid=threadIdx.x, tx=tid%16, ty=tid/16;
  for(int t=tid;t<CP*64;t+=256){
    int c=t/64, e=t%64;
    W[c][e] = (c<C)? wecAT[(size_t)c*Cout + o0+e] : 0.f;
  }
  const float* Eb=EE+(size_t)bz*(size_t)C*KN;
  const float* t3b=T3+(size_t)b*Cout*NP;
  float t3r[4][4];
  #pragma unroll
  for(int ii=0;ii<4;ii++)
    #pragma unroll
    for(int jj=0;jj<4;jj++)
      t3r[ii][jj]=t3b[(size_t)(o0+ty*4+ii)*NP + n0+tx*4+jj];
  __syncthreads();
  float mx[4][4], mn[4][4], smr[4]={0,0,0,0}, ssr[4]={0,0,0,0};
  #pragma unroll
  for(int ii=0;ii<4;ii++)
    #pragma unroll
    for(int jj=0;jj<4;jj++){ mx[ii][jj]=-FLT_MAX; mn[ii][jj]=FLT_MAX; }
  for(int k=0;k<KK;k++){
    float acc[4][4]={};
    for(int c0=0;c0<C;c0+=16){
      #pragma unroll
      for(int r=0;r<4;r++){
        int tl=tid+256*r;
        int c=tl/64, e=tl%64;
        int cg=c0+c;
        Bt[c][e] = (cg<C)? Eb[(size_t)cg*KN + k*NP + n0+e] : 0.f;
      }
      __syncthreads();
      for(int c=0;c<16;c++){
        float4 w4=*(const float4*)&W[c0+c][ty*4];
        float4 b4=*(const float4*)&Bt[c][tx*4];
        float wr[4]={w4.x,w4.y,w4.z,w4.w}, br[4]={b4.x,b4.y,b4.z,b4.w};
        #pragma unroll
        for(int ii=0;ii<4;ii++)
          #pragma unroll
          for(int jj=0;jj<4;jj++) acc[ii][jj] += wr[ii]*br[jj];
      }
      __syncthreads();
    }
    #pragma unroll
    for(int ii=0;ii<4;ii++){
      float rs=0.f, rss=0.f;
      #pragma unroll
      for(int jj=0;jj<4;jj++){
        float y=acc[ii][jj]+t3r[ii][jj];
        mx[ii][jj]=fmaxf(mx[ii][jj],y);
        mn[ii][jj]=fminf(mn[ii][jj],y);
        rs+=y; rss+=y*y;
      }
      smr[ii]+=rs; ssr[ii]+=rss;
    }
  }
  #pragma unroll
  for(int ii=0;ii<4;ii++){
    int oo=o0+ty*4+ii;
    float4 v4; v4.x=mx[ii][0]; v4.y=mx[ii][1]; v4.z=mx[ii][2]; v4.w=mx[ii][3];
    *(float4*)&ymx[((size_t)b*Cout+oo)*NP + n0+tx*4] = v4;
    v4.x=mn[ii][0]; v4.y=mn[ii][1]; v4.z=mn[ii][2]; v4.w=mn[ii][3];
    *(float4*)&ymn[((size_t)b*Cout+oo)*NP + n0+tx*4] = v4;
  }
  #pragma unroll
  for(int off=1;off<16;off<<=1){
    #pragma unroll
    for(int ii=0;ii<4;ii++){
      smr[ii]+=__shfl_xor(smr[ii],off,64);
      ssr[ii]+=__shfl_xor(ssr[ii],off,64);
    }
  }
  if(tx==0){
    #pragma unroll
    for(int ii=0;ii<4;ii++){
      atomicAdd(&sumb[o0+ty*4+ii], smr[ii]);
      atomicAdd(&ssqb[o0+ty*4+ii], ssr[ii]);
    }
  }
}

__global__ void k_bnprep(const float* __restrict__ sumb, const float* __restrict__ ssqb,
                         const float* __restrict__ gg, const float* __restrict__ bb,
                         float* __restrict__ sct, int Cout, float invcnt){
  int o=blockIdx.x*256+threadIdx.x;
  if(o>=Cout)return;
  float m=sumb[o]*invcnt;
  float v=ssqb[o]*invcnt-m*m;
  float s=gg[o]*rsqrtf(v+BEPS);
  sct[o]=s; sct[Cout+o]=bb[o]-s*m;
}

__global__ void k_stageout(const float* __restrict__ ymaxb, const float* __restrict__ yminb,
                           const float* __restrict__ sct, float* __restrict__ xo, int Cout, size_t obs){
  int t=blockIdx.x*256+threadIdx.x;
  if(t>=BB*Cout*NP)return;
  int n=t%NP; int r=t/NP; int o=r%Cout; int b=r/Cout;
  float s=sct[o], tt=sct[Cout+o];
  float y = s>=0.f ? fmaf(s,ymaxb[t],tt) : fmaf(s,yminb[t],tt);
  xo[(size_t)b*obs + (size_t)o*NP + n]=fmaxf(y,0.f);
}

__global__ void k_stats(const float* __restrict__ y, const float* __restrict__ gg, const float* __restrict__ bb,
                        float* __restrict__ sct, int Cch){
  int o=blockIdx.x;
  float s=0.f, ss=0.f;
  for(int t=threadIdx.x;t<BB*NP;t+=256){
    int b=t/NP, n=t%NP;
    float v=y[((size_t)b*Cch+o)*NP+n];
    s+=v; ss+=v*v;
  }
  __shared__ float r1[256], r2[256];
  r1[threadIdx.x]=s; r2[threadIdx.x]=ss;
  __syncthreads();
  for(int st=128;st>0;st>>=1){
    if(threadIdx.x<st){ r1[threadIdx.x]+=r1[threadIdx.x+st]; r2[threadIdx.x]+=r2[threadIdx.x+st]; }
    __syncthreads();
  }
  if(threadIdx.x==0){
    float m=r1[0]/(float)(BB*NP);
    float v=r2[0]/(float)(BB*NP)-m*m;
    float sc=gg[o]*rsqrtf(v+BEPS);
    sct[o]=sc; sct[Cch+o]=bb[o]-sc*m;
  }
}

__global__ void k_gvec(const float* __restrict__ y, const float* __restrict__ sct,
                       float* __restrict__ gv, int Cch, int gstride){
  int blk=blockIdx.x; int b=blk/Cch, o=blk%Cch;
  float sc=sct[o], sh=sct[Cch+o];
  float m=-FLT_MAX;
  for(int n=threadIdx.x;n<NP;n+=256) m=fmaxf(m, fmaf(sc,y[((size_t)b*Cch+o)*NP+n],sh));
  __shared__ float r[256];
  r[threadIdx.x]=m; __syncthreads();
  for(int st=128;st>0;st>>=1){ if(threadIdx.x<st) r[threadIdx.x]=fmaxf(r[threadIdx.x],r[threadIdx.x+st]); __syncthreads(); }
  if(threadIdx.x==0) gv[(size_t)b*gstride+o]=fmaxf(r[0],0.f);
}

__global__ void k_t6(const float* __restrict__ gvec, const float* __restrict__ w6, float* __restrict__ t6b){
  int t=blockIdx.x*256+threadIdx.x;
  if(t>=BB*512)return;
  int b=t/512, o=t%512;
  const float* w=w6+(size_t)o*1152+128;
  const float* gv=gvec+(size_t)b*1024;
  float s=0.f;
  for(int c=0;c<1024;c++) s+=w[c]*gv[c];
  t6b[t]=s;
}

__global__ void k_norm(float* __restrict__ y, const float* __restrict__ sct, int Cch, int total){
  int t=blockIdx.x*256+threadIdx.x;
  if(t>=total)return;
  int o=(t/NP)%Cch;
  y[t]=fmaxf(fmaf(sct[o],y[t],sct[Cch+o]),0.f);
}

} // namespace

extern "C" void kernel_launch(void* const* d_in, const int* in_sizes, int n_in,
                              void* d_out, int out_size, void* d_ws, size_t ws_size,
                              hipStream_t stream){
  const float* x   =(const float*)d_in[0];
  const float* wa_1[4]={(const float*)d_in[1],(const float*)d_in[3],(const float*)d_in[5],(const float*)d_in[7]};
  const float* wa_2[4]={(const float*)d_in[2],(const float*)d_in[4],(const float*)d_in[6],(const float*)d_in[8]};
  const float* wfn[4]={(const float*)d_in[9],(const float*)d_in[10],(const float*)d_in[11],(const float*)d_in[12]};
  const float* wec[4]={(const float*)d_in[13],(const float*)d_in[14],(const float*)d_in[15],(const float*)d_in[16]};
  const float* w5=(const float*)d_in[17];
  const float* w6=(const float*)d_in[18];
  const float* w7=(const float*)d_in[19];
  const float* w8=(const float*)d_in[20];
  const float* gs[7]; const float* bs[7];
  for(int i=0;i<7;i++){ gs[i]=(const float*)d_in[21+2*i]; bs[i]=(const float*)d_in[22+2*i]; }

  const int Cs[4]={10,64,64,128};
  const int Co[4]={64,64,128,256};
  const size_t U=(size_t)BB*NP;

  float* base=(float*)d_ws;
  size_t off=0;
  auto alloc=[&](size_t nfl)->float*{ float* p=base+off; off+=(nfl+3)&~(size_t)3; return p; };

  // fixed buffers
  float* f_buf = alloc(10*U);
  float* xcat  = alloc(512*U);
  float* sq    = alloc(U);
  int*   idxb  = (int*)alloc(20*U);
  float* T2    = alloc(128*U);
  float* R2    = alloc(256*U);      // nbm then T3
  float* ymx   = alloc(256*U);
  float* ymn   = alloc(256*U);
  float* sums  = alloc(2048);
  float* sct   = alloc(4096);
  float* gvecb = alloc(4096);
  float* t6b   = alloc(2048);
  float* meanxb= alloc(16);
  // transposed weights
  float* wa1T[4]; float* wa2T[4]; float* wecAT[4]; float* wecBT[4]; float* wecGT[4]; float* wfnT[4];
  for(int s=0;s<4;s++){
    int C=Cs[s], Cout=Co[s];
    wa1T[s]=alloc((size_t)C*C); wa2T[s]=alloc((size_t)C*C);
    wecAT[s]=alloc((size_t)C*Cout); wecBT[s]=alloc((size_t)C*Cout);
    wecGT[s]=alloc((size_t)512*Cout); wfnT[s]=alloc((size_t)2*C*512);
  }
  float* w5T=alloc((size_t)512*1024); float* w6mT=alloc((size_t)128*512);
  float* w7T=alloc((size_t)512*256);  float* w8T=alloc((size_t)256*50);

  // R1 region: hosts Dbuf / gfb / AEE(nb batches) / head (y6+y7)
  size_t headF = 768*U;                       // y6 (512U) + y7 (256U); also >= y5h (512U), Dbuf, gfb
  size_t remaining = (ws_size/4 > off)? (ws_size/4 - off) : 0;
  int nb = 1;
  for(int cand=4; cand>=1; cand>>=1){
    size_t need = headF;
    size_t aee = (size_t)cand*(size_t)128*KN;
    if(aee>need) need=aee;
    if(need<=remaining){ nb=cand; break; }
    if(cand==1) nb=1;
  }
  size_t R1F = headF;
  { size_t aee=(size_t)nb*(size_t)128*KN; if(aee>R1F) R1F=aee; }
  float* R1 = alloc(R1F);
  float* Dbuf=R1; float* gfb=R1; float* AEE=R1;
  float* y5h=R1; float* y6=R1; float* y7=R1+512*U;
  float* nbm=R2; float* T3=R2;

  hipMemsetAsync(sums,0,2048*sizeof(float),stream);

  for(int s=0;s<4;s++){
    int C=Cs[s], Cout=Co[s], Cin=2*C+512;
    k_transpose<<<(C*C+255)/256,256,0,stream>>>(wa_1[s],wa1T[s],C,C,C,0);
    k_transpose<<<(C*C+255)/256,256,0,stream>>>(wa_2[s],wa2T[s],C,C,C,0);
    k_transpose<<<(C*Cout+255)/256,256,0,stream>>>(wec[s],wecAT[s],Cout,C,Cin,0);
    k_transpose<<<(C*Cout+255)/256,256,0,stream>>>(wec[s],wecBT[s],Cout,C,Cin,C);
    k_transpose<<<(512*Cout+255)/256,256,0,stream>>>(wec[s],wecGT[s],Cout,512,Cin,2*C);
    k_transpose<<<(2*C*512+255)/256,256,0,stream>>>(wfn[s],wfnT[s],512,2*C,2*C,0);
  }
  k_transpose<<<(512*1024+255)/256,256,0,stream>>>(w5,w5T,1024,512,512,0);
  k_transpose<<<(128*512+255)/256,256,0,stream>>>(w6,w6mT,512,128,1152,0);
  k_transpose<<<(512*256+255)/256,256,0,stream>>>(w7,w7T,256,512,512,0);
  k_transpose<<<(256*50+255)/256,256,0,stream>>>(w8,w8T,50,256,256,0);

  k_meanx<<<12,256,0,stream>>>(x,meanxb);
  k_repsurf<<<(BB*NP+255)/256,256,0,stream>>>(x,meanxb,f_buf);

  const float* xin[4]={f_buf, xcat, xcat+(size_t)64*NP, xcat+(size_t)128*NP};
  const size_t BSs[4]={(size_t)10*NP,(size_t)512*NP,(size_t)512*NP,(size_t)512*NP};
  float* xoutb[4]={xcat, xcat+(size_t)64*NP, xcat+(size_t)128*NP, xcat+(size_t)256*NP};

  for(int s=0;s<4;s++){
    int C=Cs[s], Cout=Co[s];
    size_t BS=BSs[s];
    k_sqnorm<<<(int)((U+255)/256),256,0,stream>>>(xin[s],BS,sq,C);
    for(int b=0;b<BB;b++){
      k_dist<<<dim3(32,32),256,0,stream>>>(xin[s]+(size_t)b*BS, sq+(size_t)b*NP, Dbuf, C);
      k_topk<<<NP/4,256,0,stream>>>(Dbuf, idxb+(size_t)b*NP*KK);
    }
    k_nbmax<<<(int)((BB*(size_t)C*NP+255)/256),256,0,stream>>>(xin[s],BS,idxb,nbm,C);
    // gf = relu(Wfn @ [x; nbmax])
    k_gemm<1><<<dim3(32,8,BB),256,0,stream>>>(wfnT[s],512,512,2*C, xin[s],BS,C, nbm,(size_t)C*NP,
                                              nullptr,0, gfb,(size_t)512*NP, NP);
    // T3 = WecG @ gf ; then T3 += WecB @ x (in place)
    k_gemm<0><<<dim3(32,Cout/64,BB),256,0,stream>>>(wecGT[s],Cout,Cout,512, gfb,(size_t)512*NP,512,
                                              nullptr,0, nullptr,0, T3,(size_t)Cout*NP, NP);
    k_gemm<2><<<dim3(32,Cout/64,BB),256,0,stream>>>(wecBT[s],Cout,Cout,C, xin[s],BS,C,
                                              nullptr,0, T3,(size_t)Cout*NP, T3,(size_t)Cout*NP, NP);
    // T2 = Wa2 @ x
    k_gemm<0><<<dim3(32,(C+63)/64,BB),256,0,stream>>>(wa2T[s],C,C,C, xin[s],BS,C,
                                              nullptr,0, nullptr,0, T2,(size_t)C*NP, NP);
    float* sb=sums+(size_t)s*512; float* qb=sb+256;
    for(int bc=0;bc<BB;bc+=nb){
      if(C==10){
        k_gatherA<10><<<dim3(KN/64,1,nb),256,0,stream>>>(xin[s],BS,idxb,wa1T[s],T2,AEE,bc);
        k_smscale<10><<<dim3(KN/256,1,nb),256,0,stream>>>(AEE,xin[s],BS,idxb,bc);
        k_yfold<10,64><<<dim3(NP/64,1,nb),256,0,stream>>>(AEE,wecAT[s],T3,ymx,ymn,sb,qb,bc);
      } else if(C==64 && Cout==64){
        k_gatherA<64><<<dim3(KN/64,1,nb),256,0,stream>>>(xin[s],BS,idxb,wa1T[s],T2,AEE,bc);
        k_smscale<64><<<dim3(KN/256,1,nb),256,0,stream>>>(AEE,xin[s],BS,idxb,bc);
        k_yfold<64,64><<<dim3(NP/64,1,nb),256,0,stream>>>(AEE,wecAT[s],T3,ymx,ymn,sb,qb,bc);
      } else if(C==64){
        k_gatherA<64><<<dim3(KN/64,1,nb),256,0,stream>>>(xin[s],BS,idxb,wa1T[s],T2,AEE,bc);
        k_smscale<64><<<dim3(KN/256,1,nb),256,0,stream>>>(AEE,xin[s],BS,idxb,bc);
        k_yfold<64,128><<<dim3(NP/64,2,nb),256,0,stream>>>(AEE,wecAT[s],T3,ymx,ymn,sb,qb,bc);
      } else {
        k_gatherA<128><<<dim3(KN/64,2,nb),256,0,stream>>>(xin[s],BS,idxb,wa1T[s],T2,AEE,bc);
        k_smscale<128><<<dim3(KN/256,1,nb),256,0,stream>>>(AEE,xin[s],BS,idxb,bc);
        k_yfold<128,256><<<dim3(NP/64,4,nb),256,0,stream>>>(AEE,wecAT[s],T3,ymx,ymn,sb,qb,bc);
      }
    }
    k_bnprep<<<1,256,0,stream>>>(sb,qb,gs[s],bs[s],sct,Cout,1.f/(float)((size_t)BB*NP*KK));
    k_stageout<<<(int)((BB*(size_t)Cout*NP+255)/256),256,0,stream>>>(ymx,ymn,sct,xoutb[s],Cout,(size_t)512*NP);
  }

  // head: y5 in two 512-channel halves
  for(int h=0;h<2;h++){
    k_gemm<0><<<dim3(32,8,BB),256,0,stream>>>(w5T+(size_t)h*512,1024,512,512, xcat,(size_t)512*NP,512,
                                              nullptr,0, nullptr,0, y5h,(size_t)512*NP, NP);
    k_stats<<<512,256,0,stream>>>(y5h,gs[4]+h*512,bs[4]+h*512,sct,512);
    k_gvec<<<BB*512,256,0,stream>>>(y5h,sct,gvecb+h*512,512,1024);
  }
  k_t6<<<(BB*512+255)/256,256,0,stream>>>(gvecb,w6,t6b);
  k_gemm<3><<<dim3(32,8,BB),256,0,stream>>>(w6mT,512,512,128, xcat+(size_t)128*NP,(size_t)512*NP,128,
                                            nullptr,0, t6b,512, y6,(size_t)512*NP, NP);
  k_stats<<<512,256,0,stream>>>(y6,gs[5],bs[5],sct,512);
  k_norm<<<(int)((BB*(size_t)512*NP+255)/256),256,0,stream>>>(y6,sct,512,(int)(BB*512*NP));
  k_gemm<0><<<dim3(32,4,BB),256,0,stream>>>(w7T,256,256,512, y6,(size_t)512*NP,512,
                                            nullptr,0, nullptr,0, y7,(size_t)256*NP, NP);
  k_stats<<<256,256,0,stream>>>(y7,gs[6],bs[6],sct,256);
  k_norm<<<(int)((BB*(size_t)256*NP+255)/256),256,0,stream>>>(y7,sct,256,(int)(BB*256*NP));
  k_gemm<1><<<dim3(32,1,BB),256,0,stream>>>(w8T,50,50,256, y7,(size_t)256*NP,256,
                                            nullptr,0, nullptr,0, (float*)d_out,(size_t)50*NP, NP);

  (void)in_sizes; (void)n_in; (void)out_size;
}

// Round 5
// 3395.708 us; speedup vs baseline: 1.6016x; 1.3031x over previous
//
#include <hip/hip_runtime.h>
#include <float.h>
#include <math.h>

namespace {

constexpr int BB = 4;
constexpr int NP = 2048;
constexpr int KK = 20;
constexpr int KN = KK*NP;          // 40960
constexpr float NEGS = 0.2f;
constexpr float BEPS = 1e-5f;

__global__ void k_meanx(const float* __restrict__ x, float* __restrict__ meanx){
  int bc = blockIdx.x;
  const float* p = x + (size_t)bc*NP;
  float s=0.f;
  for(int n=threadIdx.x;n<NP;n+=256) s+=p[n];
  __shared__ float red[256];
  red[threadIdx.x]=s; __syncthreads();
  for(int st=128;st>0;st>>=1){ if(threadIdx.x<st) red[threadIdx.x]+=red[threadIdx.x+st]; __syncthreads(); }
  if(threadIdx.x==0) meanx[bc]=red[0]/(float)NP;
}

__global__ void k_repsurf(const float* __restrict__ x, const float* __restrict__ meanx, float* __restrict__ f){
  int t=blockIdx.x*256+threadIdx.x;
  if(t>=BB*NP) return;
  int b=t/NP, n=t%NP;
  float p0=x[(b*3+0)*NP+n], p1=x[(b*3+1)*NP+n], p2=x[(b*3+2)*NP+n];
  float c0=p0-meanx[b*3+0], c1=p1-meanx[b*3+1], c2=p2-meanx[b*3+2];
  float r=sqrtf(p0*p0+p1*p1+p2*p2);
  float* fb=f+(size_t)b*10*NP+n;
  fb[0]=p0; fb[NP]=p1; fb[2*NP]=p2;
  fb[3*NP]=c0; fb[4*NP]=c1; fb[5*NP]=c2;
  fb[6*NP]=p0*p0; fb[7*NP]=p1*p1; fb[8*NP]=p2*p2;
  fb[9*NP]=r;
}

// out[s*R + r] = in[r*rs + off + s]
__global__ void k_transpose(const float* __restrict__ in, float* __restrict__ out, int R, int S, int rs, int off){
  int t=blockIdx.x*256+threadIdx.x;
  if(t>=R*S) return;
  int s=t/R, r=t%R;
  out[(size_t)s*R+r] = in[(size_t)r*rs + off + s];
}

__global__ void k_sqnorm(const float* __restrict__ x, size_t BS, float* __restrict__ sq, int C){
  int t=blockIdx.x*256+threadIdx.x;
  if(t>=BB*NP)return;
  int b=t/NP, n=t%NP;
  const float* xb=x+(size_t)b*BS+n;
  float s=0.f;
  for(int c=0;c<C;c++){ float v=xb[(size_t)c*NP]; s+=v*v; }
  sq[t]=s;
}

// 128x128 tile, 8x8 micro-tile distance GEMM (per batch)
__global__ __launch_bounds__(256) void k_dist(const float* __restrict__ xb, const float* __restrict__ sqb,
                                              float* __restrict__ D, int C){
  __shared__ __align__(16) float At[16][128];
  __shared__ __align__(16) float Bt[16][128];
  int j0 = blockIdx.x*128, i0 = blockIdx.y*128;
  int tx = threadIdx.x%16, ty = threadIdx.x/16;
  float acc[8][8]={};
  for(int c0=0;c0<C;c0+=16){
    #pragma unroll
    for(int r=0;r<8;r++){
      int tl = threadIdx.x + 256*r;
      int c = tl>>7, e = tl&127;
      int cg = c0+c;
      At[c][e] = (cg<C)? xb[(size_t)cg*NP + i0 + e] : 0.f;
    }
    #pragma unroll
    for(int r=0;r<8;r++){
      int tl = threadIdx.x + 256*r;
      int c = tl>>7, e = tl&127;
      int cg = c0+c;
      Bt[c][e] = (cg<C)? xb[(size_t)cg*NP + j0 + e] : 0.f;
    }
    __syncthreads();
    int cm = (C-c0 < 16)? (C-c0) : 16;
    for(int c=0;c<cm;c++){
      float4 a0=*(const float4*)&At[c][ty*8];
      float4 a1=*(const float4*)&At[c][ty*8+4];
      float4 b0=*(const float4*)&Bt[c][tx*8];
      float4 b1=*(const float4*)&Bt[c][tx*8+4];
      float ar[8]={a0.x,a0.y,a0.z,a0.w,a1.x,a1.y,a1.z,a1.w};
      float br[8]={b0.x,b0.y,b0.z,b0.w,b1.x,b1.y,b1.z,b1.w};
      #pragma unroll
      for(int ii=0;ii<8;ii++)
        #pragma unroll
        for(int jj=0;jj<8;jj++) acc[ii][jj] += ar[ii]*br[jj];
    }
    __syncthreads();
  }
  #pragma unroll
  for(int ii=0;ii<8;ii++){
    int i=i0+ty*8+ii;
    float si=sqb[i];
    #pragma unroll
    for(int jq=0;jq<2;jq++){
      int j=j0+tx*8+jq*4;
      float4 w;
      w.x = si + sqb[j+0] - 2.f*acc[ii][jq*4+0];
      w.y = si + sqb[j+1] - 2.f*acc[ii][jq*4+1];
      w.z = si + sqb[j+2] - 2.f*acc[ii][jq*4+2];
      w.w = si + sqb[j+3] - 2.f*acc[ii][jq*4+3];
      *(float4*)&D[(size_t)i*NP + j] = w;
    }
  }
}

__global__ __launch_bounds__(256) void k_topk(const float* __restrict__ D, int* __restrict__ out){
  int wid = threadIdx.x>>6, lane = threadIdx.x&63;
  int row = blockIdx.x*4 + wid;
  const float* d = D + (size_t)row*NP;
  unsigned long long r[20];
  #pragma unroll
  for(int q=0;q<20;q++) r[q]=~0ULL;
  for(int t=0;t<NP/64;t++){
    int j = lane + 64*t;
    float v = d[j];
    unsigned u = __float_as_uint(v);
    u = (u & 0x80000000u) ? ~u : (u | 0x80000000u);
    unsigned long long key = ((unsigned long long)u<<32) | (unsigned)j;
    #pragma unroll
    for(int q=0;q<20;q++){
      unsigned long long lo = key<r[q]?key:r[q];
      unsigned long long hi = key<r[q]?r[q]:key;
      r[q]=lo; key=hi;
    }
  }
  int* o = out + (size_t)row*KK;
  for(int kk=0;kk<KK;kk++){
    unsigned long long m = r[0];
    #pragma unroll
    for(int off=1;off<64;off<<=1){
      unsigned long long ot = __shfl_xor(m, off, 64);
      if(ot<m) m=ot;
    }
    if(lane==0) o[kk] = (int)(unsigned)(m & 0xffffffffULL);
    if(r[0]==m){
      #pragma unroll
      for(int q=0;q<19;q++) r[q]=r[q+1];
      r[19]=~0ULL;
    }
  }
}

__global__ void k_nbmax(const float* __restrict__ x, size_t BS, const int* __restrict__ idx,
                        float* __restrict__ nbm, int C){
  int t=blockIdx.x*256+threadIdx.x;
  if(t>=BB*C*NP)return;
  int n=t%NP; int bc=t/NP; int c=bc%C; int b=bc/C;
  const int* id=idx+((size_t)b*NP+n)*KK;
  const float* xr=x+(size_t)b*BS+(size_t)c*NP;
  float m=-FLT_MAX;
  for(int k=0;k<KK;k++) m=fmaxf(m,xr[id[k]]);
  nbm[t]=m;
}

// generic tiled GEMM: out[b][o][col] = WT^T @ B (+epilogue)
// EPI: 0 none, 1 relu, 2 add tensor, 3 bias per (b,o), 4 subtract tensor
template<int EPI>
__global__ __launch_bounds__(256) void k_gemm(
    const float* __restrict__ WT, int Os, int O, int Cin,
    const float* __restrict__ B1, size_t bs1, int split,
    const float* __restrict__ B2, size_t bs2,
    const float* __restrict__ ADD, size_t abs_,
    float* __restrict__ out, size_t obs, int ncols){
  __shared__ __align__(16) float At[16][64];
  __shared__ __align__(16) float Bt[16][64];
  int n0=blockIdx.x*64, o0=blockIdx.y*64, b=blockIdx.z;
  int tx=threadIdx.x%16, ty=threadIdx.x/16;
  float acc[4][4]={};
  for(int c0=0;c0<Cin;c0+=16){
    #pragma unroll
    for(int r=0;r<4;r++){
      int tl=threadIdx.x+256*r;
      int c=tl/64, e=tl%64;
      int cg=c0+c;
      At[c][e] = (cg<Cin && o0+e<O)? WT[(size_t)cg*Os + o0+e] : 0.f;
      float bv=0.f;
      if(cg<Cin){
        bv = (cg<split)? B1[(size_t)b*bs1 + (size_t)cg*ncols + n0+e]
                       : B2[(size_t)b*bs2 + (size_t)(cg-split)*ncols + n0+e];
      }
      Bt[c][e]=bv;
    }
    __syncthreads();
    int cm = (Cin-c0 < 16)? (Cin-c0) : 16;
    for(int c=0;c<cm;c++){
      float4 a4=*(const float4*)&At[c][ty*4];
      float4 b4=*(const float4*)&Bt[c][tx*4];
      float ar[4]={a4.x,a4.y,a4.z,a4.w}, br[4]={b4.x,b4.y,b4.z,b4.w};
      #pragma unroll
      for(int ii=0;ii<4;ii++)
        #pragma unroll
        for(int jj=0;jj<4;jj++) acc[ii][jj] += ar[ii]*br[jj];
    }
    __syncthreads();
  }
  #pragma unroll
  for(int ii=0;ii<4;ii++){
    int oo=o0+ty*4+ii;
    if(oo<O){
      #pragma unroll
      for(int jj=0;jj<4;jj++){
        int col=n0+tx*4+jj;
        float v=acc[ii][jj];
        if constexpr (EPI==2) v += ADD[(size_t)b*abs_ + (size_t)oo*ncols + col];
        if constexpr (EPI==4) v -= ADD[(size_t)b*abs_ + (size_t)oo*ncols + col];
        if constexpr (EPI==3) v += ADD[(size_t)b*abs_ + oo];
        if constexpr (EPI==1) v = fmaxf(v,0.f);
        out[(size_t)b*obs + (size_t)oo*ncols + col]=v;
      }
    }
  }
}

// attention + softmax + scale, fully decomposed:
// a[c] = leaky(P1[c][id] + Q[c][n]);  EE[c][col] = softmax_c(a) * (x[c][id]-x[c][n])
template<int C>
__global__ void k_attn(const float* __restrict__ x, size_t BS, const int* __restrict__ idx,
                       const float* __restrict__ P1, const float* __restrict__ Q,
                       float* __restrict__ EE, int b0){
  int col=blockIdx.x*256+threadIdx.x;
  int bz=blockIdx.z, b=b0+bz;
  int n=col&(NP-1), k=col>>11;
  int id=idx[((size_t)b*NP+n)*KK+k];
  const float* p1=P1+(size_t)b*C*NP;
  const float* q =Q +(size_t)b*C*NP;
  float m=-FLT_MAX;
  for(int c=0;c<C;c++){
    float a=p1[(size_t)c*NP+id]+q[(size_t)c*NP+n];
    a = a>0.f? a : NEGS*a;
    m=fmaxf(m,a);
  }
  float s=0.f;
  for(int c=0;c<C;c++){
    float a=p1[(size_t)c*NP+id]+q[(size_t)c*NP+n];
    a = a>0.f? a : NEGS*a;
    s+=__expf(a-m);
  }
  float rs=1.f/s;
  const float* xs=x+(size_t)b*BS;
  float* Eb=EE+(size_t)bz*(size_t)C*KN+col;
  for(int c=0;c<C;c++){
    float a=p1[(size_t)c*NP+id]+q[(size_t)c*NP+n];
    a = a>0.f? a : NEGS*a;
    float e=__expf(a-m)*rs;
    Eb[(size_t)c*KN]=e*(xs[(size_t)c*NP+id]-xs[(size_t)c*NP+n]);
  }
}

// Y = WecA @ EE + T3, fold stats over k inside the block (Y never materialized).
// Full-C LDS staging per k: 2 barriers per k.
template<int C, int Cout>
__global__ __launch_bounds__(256) void k_yfold(
    const float* __restrict__ EE,     // [bz][C][KN]
    const float* __restrict__ wecAT,  // [C][Cout]
    const float* __restrict__ T3,     // [b][Cout][NP] full-batch
    float* __restrict__ ymx, float* __restrict__ ymn,
    float* __restrict__ sumb, float* __restrict__ ssqb, int b0){
  constexpr int CP=((C+15)/16)*16;
  __shared__ __align__(16) float W[CP][64];
  __shared__ __align__(16) float Bt[CP][64];
  int n0=blockIdx.x*64, o0=blockIdx.y*64, bz=blockIdx.z, b=b0+bz;
  int tid=threadIdx.x, tx=tid%16, ty=tid/16;
  for(int t=tid;t<CP*64;t+=256){
    int c=t/64, e=t%64;
    W[c][e] = (c<C)? wecAT[(size_t)c*Cout + o0+e] : 0.f;
  }
  const float* Eb=EE+(size_t)bz*(size_t)C*KN;
  const float* t3b=T3+(size_t)b*Cout*NP;
  float t3r[4][4];
  #pragma unroll
  for(int ii=0;ii<4;ii++)
    #pragma unroll
    for(int jj=0;jj<4;jj++)
      t3r[ii][jj]=t3b[(size_t)(o0+ty*4+ii)*NP + n0+tx*4+jj];
  float mx[4][4], mn[4][4], smr[4]={0,0,0,0}, ssr[4]={0,0,0,0};
  #pragma unroll
  for(int ii=0;ii<4;ii++)
    #pragma unroll
    for(int jj=0;jj<4;jj++){ mx[ii][jj]=-FLT_MAX; mn[ii][jj]=FLT_MAX; }
  __syncthreads();
  for(int k=0;k<KK;k++){
    for(int t=tid;t<CP*64;t+=256){
      int c=t/64, e=t%64;
      Bt[c][e] = (c<C)? Eb[(size_t)c*KN + (size_t)k*NP + n0+e] : 0.f;
    }
    __syncthreads();
    float acc[4][4]={};
    for(int c=0;c<C;c++){
      float4 w4=*(const float4*)&W[c][ty*4];
      float4 b4=*(const float4*)&Bt[c][tx*4];
      float wr[4]={w4.x,w4.y,w4.z,w4.w}, br[4]={b4.x,b4.y,b4.z,b4.w};
      #pragma unroll
      for(int ii=0;ii<4;ii++)
        #pragma unroll
        for(int jj=0;jj<4;jj++) acc[ii][jj] += wr[ii]*br[jj];
    }
    #pragma unroll
    for(int ii=0;ii<4;ii++){
      float rs=0.f, rss=0.f;
      #pragma unroll
      for(int jj=0;jj<4;jj++){
        float y=acc[ii][jj]+t3r[ii][jj];
        mx[ii][jj]=fmaxf(mx[ii][jj],y);
        mn[ii][jj]=fminf(mn[ii][jj],y);
        rs+=y; rss+=y*y;
      }
      smr[ii]+=rs; ssr[ii]+=rss;
    }
    __syncthreads();
  }
  #pragma unroll
  for(int ii=0;ii<4;ii++){
    int oo=o0+ty*4+ii;
    float4 v4; v4.x=mx[ii][0]; v4.y=mx[ii][1]; v4.z=mx[ii][2]; v4.w=mx[ii][3];
    *(float4*)&ymx[((size_t)b*Cout+oo)*NP + n0+tx*4] = v4;
    v4.x=mn[ii][0]; v4.y=mn[ii][1]; v4.z=mn[ii][2]; v4.w=mn[ii][3];
    *(float4*)&ymn[((size_t)b*Cout+oo)*NP + n0+tx*4] = v4;
  }
  #pragma unroll
  for(int off=1;off<16;off<<=1){
    #pragma unroll
    for(int ii=0;ii<4;ii++){
      smr[ii]+=__shfl_xor(smr[ii],off,64);
      ssr[ii]+=__shfl_xor(ssr[ii],off,64);
    }
  }
  if(tx==0){
    #pragma unroll
    for(int ii=0;ii<4;ii++){
      atomicAdd(&sumb[o0+ty*4+ii], smr[ii]);
      atomicAdd(&ssqb[o0+ty*4+ii], ssr[ii]);
    }
  }
}

__global__ void k_bnprep(const float* __restrict__ sumb, const float* __restrict__ ssqb,
                         const float* __restrict__ gg, const float* __restrict__ bb,
                         float* __restrict__ sct, int Cout, float invcnt){
  int o=blockIdx.x*256+threadIdx.x;
  if(o>=Cout)return;
  float m=sumb[o]*invcnt;
  float v=ssqb[o]*invcnt-m*m;
  float s=gg[o]*rsqrtf(v+BEPS);
  sct[o]=s; sct[Cout+o]=bb[o]-s*m;
}

__global__ void k_stageout(const float* __restrict__ ymaxb, const float* __restrict__ yminb,
                           const float* __restrict__ sct, float* __restrict__ xo, int Cout, size_t obs){
  int t=blockIdx.x*256+threadIdx.x;
  if(t>=BB*Cout*NP)return;
  int n=t%NP; int r=t/NP; int o=r%Cout; int b=r/Cout;
  float s=sct[o], tt=sct[Cout+o];
  float y = s>=0.f ? fmaf(s,ymaxb[t],tt) : fmaf(s,yminb[t],tt);
  xo[(size_t)b*obs + (size_t)o*NP + n]=fmaxf(y,0.f);
}

__global__ void k_stats(const float* __restrict__ y, const float* __restrict__ gg, const float* __restrict__ bb,
                        float* __restrict__ sct, int Cch){
  int o=blockIdx.x;
  float s=0.f, ss=0.f;
  for(int t=threadIdx.x;t<BB*NP;t+=256){
    int b=t/NP, n=t%NP;
    float v=y[((size_t)b*Cch+o)*NP+n];
    s+=v; ss+=v*v;
  }
  __shared__ float r1[256], r2[256];
  r1[threadIdx.x]=s; r2[threadIdx.x]=ss;
  __syncthreads();
  for(int st=128;st>0;st>>=1){
    if(threadIdx.x<st){ r1[threadIdx.x]+=r1[threadIdx.x+st]; r2[threadIdx.x]+=r2[threadIdx.x+st]; }
    __syncthreads();
  }
  if(threadIdx.x==0){
    float m=r1[0]/(float)(BB*NP);
    float v=r2[0]/(float)(BB*NP)-m*m;
    float sc=gg[o]*rsqrtf(v+BEPS);
    sct[o]=sc; sct[Cch+o]=bb[o]-sc*m;
  }
}

__global__ void k_gvec(const float* __restrict__ y, const float* __restrict__ sct,
                       float* __restrict__ gv, int Cch, int gstride){
  int blk=blockIdx.x; int b=blk/Cch, o=blk%Cch;
  float sc=sct[o], sh=sct[Cch+o];
  float m=-FLT_MAX;
  for(int n=threadIdx.x;n<NP;n+=256) m=fmaxf(m, fmaf(sc,y[((size_t)b*Cch+o)*NP+n],sh));
  __shared__ float r[256];
  r[threadIdx.x]=m; __syncthreads();
  for(int st=128;st>0;st>>=1){ if(threadIdx.x<st) r[threadIdx.x]=fmaxf(r[threadIdx.x],r[threadIdx.x+st]); __syncthreads(); }
  if(threadIdx.x==0) gv[(size_t)b*gstride+o]=fmaxf(r[0],0.f);
}

__global__ void k_t6(const float* __restrict__ gvec, const float* __restrict__ w6, float* __restrict__ t6b){
  int t=blockIdx.x*256+threadIdx.x;
  if(t>=BB*512)return;
  int b=t/512, o=t%512;
  const float* w=w6+(size_t)o*1152+128;
  const float* gv=gvec+(size_t)b*1024;
  float s=0.f;
  for(int c=0;c<1024;c++) s+=w[c]*gv[c];
  t6b[t]=s;
}

__global__ void k_norm(float* __restrict__ y, const float* __restrict__ sct, int Cch, int total){
  int t=blockIdx.x*256+threadIdx.x;
  if(t>=total)return;
  int o=(t/NP)%Cch;
  y[t]=fmaxf(fmaf(sct[o],y[t],sct[Cch+o]),0.f);
}

} // namespace

extern "C" void kernel_launch(void* const* d_in, const int* in_sizes, int n_in,
                              void* d_out, int out_size, void* d_ws, size_t ws_size,
                              hipStream_t stream){
  const float* x   =(const float*)d_in[0];
  const float* wa_1[4]={(const float*)d_in[1],(const float*)d_in[3],(const float*)d_in[5],(const float*)d_in[7]};
  const float* wa_2[4]={(const float*)d_in[2],(const float*)d_in[4],(const float*)d_in[6],(const float*)d_in[8]};
  const float* wfn[4]={(const float*)d_in[9],(const float*)d_in[10],(const float*)d_in[11],(const float*)d_in[12]};
  const float* wec[4]={(const float*)d_in[13],(const float*)d_in[14],(const float*)d_in[15],(const float*)d_in[16]};
  const float* w5=(const float*)d_in[17];
  const float* w6=(const float*)d_in[18];
  const float* w7=(const float*)d_in[19];
  const float* w8=(const float*)d_in[20];
  const float* gs[7]; const float* bs[7];
  for(int i=0;i<7;i++){ gs[i]=(const float*)d_in[21+2*i]; bs[i]=(const float*)d_in[22+2*i]; }

  const int Cs[4]={10,64,64,128};
  const int Co[4]={64,64,128,256};
  const size_t U=(size_t)BB*NP;

  float* base=(float*)d_ws;
  size_t off=0;
  auto alloc=[&](size_t nfl)->float*{ float* p=base+off; off+=(nfl+3)&~(size_t)3; return p; };

  // fixed buffers
  float* f_buf = alloc(10*U);
  float* xcat  = alloc(512*U);
  float* sq    = alloc(U);
  int*   idxb  = (int*)alloc(20*U);
  float* Qb    = alloc(128*U);      // Q = Wa2.x - P1
  float* P1b   = alloc(128*U);      // P1 = Wa1.x
  float* R2    = alloc(256*U);      // nbm then T3
  float* ymx   = alloc(256*U);
  float* ymn   = alloc(256*U);
  float* sums  = alloc(2048);
  float* sct   = alloc(4096);
  float* gvecb = alloc(4096);
  float* t6b   = alloc(2048);
  float* meanxb= alloc(16);
  // transposed weights
  float* wa1T[4]; float* wa2T[4]; float* wecAT[4]; float* wecBT[4]; float* wecGT[4]; float* wfnT[4];
  for(int s=0;s<4;s++){
    int C=Cs[s], Cout=Co[s];
    wa1T[s]=alloc((size_t)C*C); wa2T[s]=alloc((size_t)C*C);
    wecAT[s]=alloc((size_t)C*Cout); wecBT[s]=alloc((size_t)C*Cout);
    wecGT[s]=alloc((size_t)512*Cout); wfnT[s]=alloc((size_t)2*C*512);
  }
  float* w5T=alloc((size_t)512*1024); float* w6mT=alloc((size_t)128*512);
  float* w7T=alloc((size_t)512*256);  float* w8T=alloc((size_t)256*50);

  // R1 region: hosts Dbuf / gfb / EE(nb batches) / head (y6+y7)
  size_t headF = 768*U;                       // y6 (512U) + y7 (256U); also >= y5h, Dbuf, gfb
  size_t remaining = (ws_size/4 > off)? (ws_size/4 - off) : 0;
  int nb = 1;
  for(int cand=4; cand>=1; cand>>=1){
    size_t need = headF;
    size_t aee = (size_t)cand*(size_t)128*KN;
    if(aee>need) need=aee;
    if(need<=remaining){ nb=cand; break; }
    if(cand==1) nb=1;
  }
  size_t R1F = headF;
  { size_t aee=(size_t)nb*(size_t)128*KN; if(aee>R1F) R1F=aee; }
  float* R1 = alloc(R1F);
  float* Dbuf=R1; float* gfb=R1; float* EEb=R1;
  float* y5h=R1; float* y6=R1; float* y7=R1+512*U;
  float* nbm=R2; float* T3=R2;

  hipMemsetAsync(sums,0,2048*sizeof(float),stream);

  for(int s=0;s<4;s++){
    int C=Cs[s], Cout=Co[s], Cin=2*C+512;
    k_transpose<<<(C*C+255)/256,256,0,stream>>>(wa_1[s],wa1T[s],C,C,C,0);
    k_transpose<<<(C*C+255)/256,256,0,stream>>>(wa_2[s],wa2T[s],C,C,C,0);
    k_transpose<<<(C*Cout+255)/256,256,0,stream>>>(wec[s],wecAT[s],Cout,C,Cin,0);
    k_transpose<<<(C*Cout+255)/256,256,0,stream>>>(wec[s],wecBT[s],Cout,C,Cin,C);
    k_transpose<<<(512*Cout+255)/256,256,0,stream>>>(wec[s],wecGT[s],Cout,512,Cin,2*C);
    k_transpose<<<(2*C*512+255)/256,256,0,stream>>>(wfn[s],wfnT[s],512,2*C,2*C,0);
  }
  k_transpose<<<(512*1024+255)/256,256,0,stream>>>(w5,w5T,1024,512,512,0);
  k_transpose<<<(128*512+255)/256,256,0,stream>>>(w6,w6mT,512,128,1152,0);
  k_transpose<<<(512*256+255)/256,256,0,stream>>>(w7,w7T,256,512,512,0);
  k_transpose<<<(256*50+255)/256,256,0,stream>>>(w8,w8T,50,256,256,0);

  k_meanx<<<12,256,0,stream>>>(x,meanxb);
  k_repsurf<<<(BB*NP+255)/256,256,0,stream>>>(x,meanxb,f_buf);

  const float* xin[4]={f_buf, xcat, xcat+(size_t)64*NP, xcat+(size_t)128*NP};
  const size_t BSs[4]={(size_t)10*NP,(size_t)512*NP,(size_t)512*NP,(size_t)512*NP};
  float* xoutb[4]={xcat, xcat+(size_t)64*NP, xcat+(size_t)128*NP, xcat+(size_t)256*NP};

  for(int s=0;s<4;s++){
    int C=Cs[s], Cout=Co[s];
    size_t BS=BSs[s];
    k_sqnorm<<<(int)((U+255)/256),256,0,stream>>>(xin[s],BS,sq,C);
    for(int b=0;b<BB;b++){
      k_dist<<<dim3(NP/128,NP/128),256,0,stream>>>(xin[s]+(size_t)b*BS, sq+(size_t)b*NP, Dbuf, C);
      k_topk<<<NP/4,256,0,stream>>>(Dbuf, idxb+(size_t)b*NP*KK);
    }
    k_nbmax<<<(int)((BB*(size_t)C*NP+255)/256),256,0,stream>>>(xin[s],BS,idxb,nbm,C);
    // gf = relu(Wfn @ [x; nbmax])
    k_gemm<1><<<dim3(32,8,BB),256,0,stream>>>(wfnT[s],512,512,2*C, xin[s],BS,C, nbm,(size_t)C*NP,
                                              nullptr,0, gfb,(size_t)512*NP, NP);
    // T3 = WecG @ gf ; then T3 += WecB @ x (in place)
    k_gemm<0><<<dim3(32,Cout/64,BB),256,0,stream>>>(wecGT[s],Cout,Cout,512, gfb,(size_t)512*NP,512,
                                              nullptr,0, nullptr,0, T3,(size_t)Cout*NP, NP);
    k_gemm<2><<<dim3(32,Cout/64,BB),256,0,stream>>>(wecBT[s],Cout,Cout,C, xin[s],BS,C,
                                              nullptr,0, T3,(size_t)Cout*NP, T3,(size_t)Cout*NP, NP);
    // P1 = Wa1 @ x ; Q = Wa2 @ x - P1
    k_gemm<0><<<dim3(32,(C+63)/64,BB),256,0,stream>>>(wa1T[s],C,C,C, xin[s],BS,C,
                                              nullptr,0, nullptr,0, P1b,(size_t)C*NP, NP);
    k_gemm<4><<<dim3(32,(C+63)/64,BB),256,0,stream>>>(wa2T[s],C,C,C, xin[s],BS,C,
                                              nullptr,0, P1b,(size_t)C*NP, Qb,(size_t)C*NP, NP);
    float* sb=sums+(size_t)s*512; float* qb=sb+256;
    for(int bc=0;bc<BB;bc+=nb){
      if(C==10){
        k_attn<10><<<dim3(KN/256,1,nb),256,0,stream>>>(xin[s],BS,idxb,P1b,Qb,EEb,bc);
        k_yfold<10,64><<<dim3(NP/64,1,nb),256,0,stream>>>(EEb,wecAT[s],T3,ymx,ymn,sb,qb,bc);
      } else if(C==64 && Cout==64){
        k_attn<64><<<dim3(KN/256,1,nb),256,0,stream>>>(xin[s],BS,idxb,P1b,Qb,EEb,bc);
        k_yfold<64,64><<<dim3(NP/64,1,nb),256,0,stream>>>(EEb,wecAT[s],T3,ymx,ymn,sb,qb,bc);
      } else if(C==64){
        k_attn<64><<<dim3(KN/256,1,nb),256,0,stream>>>(xin[s],BS,idxb,P1b,Qb,EEb,bc);
        k_yfold<64,128><<<dim3(NP/64,2,nb),256,0,stream>>>(EEb,wecAT[s],T3,ymx,ymn,sb,qb,bc);
      } else {
        k_attn<128><<<dim3(KN/256,1,nb),256,0,stream>>>(xin[s],BS,idxb,P1b,Qb,EEb,bc);
        k_yfold<128,256><<<dim3(NP/64,4,nb),256,0,stream>>>(EEb,wecAT[s],T3,ymx,ymn,sb,qb,bc);
      }
    }
    k_bnprep<<<1,256,0,stream>>>(sb,qb,gs[s],bs[s],sct,Cout,1.f/(float)((size_t)BB*NP*KK));
    k_stageout<<<(int)((BB*(size_t)Cout*NP+255)/256),256,0,stream>>>(ymx,ymn,sct,xoutb[s],Cout,(size_t)512*NP);
  }

  // head: y5 in two 512-channel halves
  for(int h=0;h<2;h++){
    k_gemm<0><<<dim3(32,8,BB),256,0,stream>>>(w5T+(size_t)h*512,1024,512,512, xcat,(size_t)512*NP,512,
                                              nullptr,0, nullptr,0, y5h,(size_t)512*NP, NP);
    k_stats<<<512,256,0,stream>>>(y5h,gs[4]+h*512,bs[4]+h*512,sct,512);
    k_gvec<<<BB*512,256,0,stream>>>(y5h,sct,gvecb+h*512,512,1024);
  }
  k_t6<<<(BB*512+255)/256,256,0,stream>>>(gvecb,w6,t6b);
  k_gemm<3><<<dim3(32,8,BB),256,0,stream>>>(w6mT,512,512,128, xcat+(size_t)128*NP,(size_t)512*NP,128,
                                            nullptr,0, t6b,512, y6,(size_t)512*NP, NP);
  k_stats<<<512,256,0,stream>>>(y6,gs[5],bs[5],sct,512);
  k_norm<<<(int)((BB*(size_t)512*NP+255)/256),256,0,stream>>>(y6,sct,512,(int)(BB*512*NP));
  k_gemm<0><<<dim3(32,4,BB),256,0,stream>>>(w7T,256,256,512, y6,(size_t)512*NP,512,
                                            nullptr,0, nullptr,0, y7,(size_t)256*NP, NP);
  k_stats<<<256,256,0,stream>>>(y7,gs[6],bs[6],sct,256);
  k_norm<<<(int)((BB*(size_t)256*NP+255)/256),256,0,stream>>>(y7,sct,256,(int)(BB*256*NP));
  k_gemm<1><<<dim3(32,1,BB),256,0,stream>>>(w8T,50,50,256, y7,(size_t)256*NP,256,
                                            nullptr,0, nullptr,0, (float*)d_out,(size_t)50*NP, NP);

  (void)in_sizes; (void)n_in; (void)out_size;
}

// Round 6
// 2996.710 us; speedup vs baseline: 1.8149x; 1.1331x over previous
//
#include <hip/hip_runtime.h>
#include <float.h>
#include <math.h>

namespace {

constexpr int BB = 4;
constexpr int NP = 2048;
constexpr int KK = 20;
constexpr float NEGS = 0.2f;
constexpr float BEPS = 1e-5f;

__global__ void k_meanx(const float* __restrict__ x, float* __restrict__ meanx){
  int bc = blockIdx.x;
  const float* p = x + (size_t)bc*NP;
  float s=0.f;
  for(int n=threadIdx.x;n<NP;n+=256) s+=p[n];
  __shared__ float red[256];
  red[threadIdx.x]=s; __syncthreads();
  for(int st=128;st>0;st>>=1){ if(threadIdx.x<st) red[threadIdx.x]+=red[threadIdx.x+st]; __syncthreads(); }
  if(threadIdx.x==0) meanx[bc]=red[0]/(float)NP;
}

__global__ void k_repsurf(const float* __restrict__ x, const float* __restrict__ meanx, float* __restrict__ f){
  int t=blockIdx.x*256+threadIdx.x;
  if(t>=BB*NP) return;
  int b=t/NP, n=t%NP;
  float p0=x[(b*3+0)*NP+n], p1=x[(b*3+1)*NP+n], p2=x[(b*3+2)*NP+n];
  float c0=p0-meanx[b*3+0], c1=p1-meanx[b*3+1], c2=p2-meanx[b*3+2];
  float r=sqrtf(p0*p0+p1*p1+p2*p2);
  float* fb=f+(size_t)b*10*NP+n;
  fb[0]=p0; fb[NP]=p1; fb[2*NP]=p2;
  fb[3*NP]=c0; fb[4*NP]=c1; fb[5*NP]=c2;
  fb[6*NP]=p0*p0; fb[7*NP]=p1*p1; fb[8*NP]=p2*p2;
  fb[9*NP]=r;
}

// out[s*R + r] = in[r*rs + off + s]  (weight transposes, small)
__global__ void k_transpose(const float* __restrict__ in, float* __restrict__ out, int R, int S, int rs, int off){
  int t=blockIdx.x*256+threadIdx.x;
  if(t>=R*S) return;
  int s=t/R, r=t%R;
  out[(size_t)s*R+r] = in[(size_t)r*rs + off + s];
}

// tiled activation transpose: in [b][C][NP] (batch stride BS) -> out [b][NP][C]
__global__ __launch_bounds__(256) void k_trT(const float* __restrict__ in, size_t BS,
                                             float* __restrict__ out, int C){
  __shared__ float t[32][33];
  int n0=blockIdx.x*32, c0=blockIdx.y*32, b=blockIdx.z;
  int tx=threadIdx.x%32, ty=threadIdx.x/32;   // ty 0..7
  #pragma unroll
  for(int r=0;r<32;r+=8){
    int c=c0+ty+r;
    t[ty+r][tx] = (c<C)? in[(size_t)b*BS + (size_t)c*NP + n0+tx] : 0.f;
  }
  __syncthreads();
  #pragma unroll
  for(int r=0;r<32;r+=8){
    int n=n0+ty+r, c=c0+tx;
    if(c<C) out[((size_t)b*NP + n)*C + c] = t[tx][ty+r];
  }
}

__global__ void k_sqnorm(const float* __restrict__ x, size_t BS, float* __restrict__ sq, int C){
  int t=blockIdx.x*256+threadIdx.x;
  if(t>=BB*NP)return;
  int b=t/NP, n=t%NP;
  const float* xb=x+(size_t)b*BS+n;
  float s=0.f;
  for(int c=0;c<C;c++){ float v=xb[(size_t)c*NP]; s+=v*v; }
  sq[t]=s;
}

// 128x128 tile, 8x8 micro-tile distance GEMM (per batch)
__global__ __launch_bounds__(256) void k_dist(const float* __restrict__ xb, const float* __restrict__ sqb,
                                              float* __restrict__ D, int C){
  __shared__ __align__(16) float At[16][128];
  __shared__ __align__(16) float Bt[16][128];
  int j0 = blockIdx.x*128, i0 = blockIdx.y*128;
  int tx = threadIdx.x%16, ty = threadIdx.x/16;
  float acc[8][8]={};
  for(int c0=0;c0<C;c0+=16){
    #pragma unroll
    for(int r=0;r<8;r++){
      int tl = threadIdx.x + 256*r;
      int c = tl>>7, e = tl&127;
      int cg = c0+c;
      At[c][e] = (cg<C)? xb[(size_t)cg*NP + i0 + e] : 0.f;
    }
    #pragma unroll
    for(int r=0;r<8;r++){
      int tl = threadIdx.x + 256*r;
      int c = tl>>7, e = tl&127;
      int cg = c0+c;
      Bt[c][e] = (cg<C)? xb[(size_t)cg*NP + j0 + e] : 0.f;
    }
    __syncthreads();
    int cm = (C-c0 < 16)? (C-c0) : 16;
    for(int c=0;c<cm;c++){
      float4 a0=*(const float4*)&At[c][ty*8];
      float4 a1=*(const float4*)&At[c][ty*8+4];
      float4 b0=*(const float4*)&Bt[c][tx*8];
      float4 b1=*(const float4*)&Bt[c][tx*8+4];
      float ar[8]={a0.x,a0.y,a0.z,a0.w,a1.x,a1.y,a1.z,a1.w};
      float br[8]={b0.x,b0.y,b0.z,b0.w,b1.x,b1.y,b1.z,b1.w};
      #pragma unroll
      for(int ii=0;ii<8;ii++)
        #pragma unroll
        for(int jj=0;jj<8;jj++) acc[ii][jj] += ar[ii]*br[jj];
    }
    __syncthreads();
  }
  #pragma unroll
  for(int ii=0;ii<8;ii++){
    int i=i0+ty*8+ii;
    float si=sqb[i];
    #pragma unroll
    for(int jq=0;jq<2;jq++){
      int j=j0+tx*8+jq*4;
      float4 w;
      w.x = si + sqb[j+0] - 2.f*acc[ii][jq*4+0];
      w.y = si + sqb[j+1] - 2.f*acc[ii][jq*4+1];
      w.z = si + sqb[j+2] - 2.f*acc[ii][jq*4+2];
      w.w = si + sqb[j+3] - 2.f*acc[ii][jq*4+3];
      *(float4*)&D[(size_t)i*NP + j] = w;
    }
  }
}

__global__ __launch_bounds__(256) void k_topk(const float* __restrict__ D, int* __restrict__ out){
  int wid = threadIdx.x>>6, lane = threadIdx.x&63;
  int row = blockIdx.x*4 + wid;
  const float* d = D + (size_t)row*NP;
  unsigned long long r[20];
  #pragma unroll
  for(int q=0;q<20;q++) r[q]=~0ULL;
  for(int t=0;t<NP/64;t++){
    int j = lane + 64*t;
    float v = d[j];
    unsigned u = __float_as_uint(v);
    u = (u & 0x80000000u) ? ~u : (u | 0x80000000u);
    unsigned long long key = ((unsigned long long)u<<32) | (unsigned)j;
    #pragma unroll
    for(int q=0;q<20;q++){
      unsigned long long lo = key<r[q]?key:r[q];
      unsigned long long hi = key<r[q]?r[q]:key;
      r[q]=lo; key=hi;
    }
  }
  int* o = out + (size_t)row*KK;
  for(int kk=0;kk<KK;kk++){
    unsigned long long m = r[0];
    #pragma unroll
    for(int off=1;off<64;off<<=1){
      unsigned long long ot = __shfl_xor(m, off, 64);
      if(ot<m) m=ot;
    }
    if(lane==0) o[kk] = (int)(unsigned)(m & 0xffffffffULL);
    if(r[0]==m){
      #pragma unroll
      for(int q=0;q<19;q++) r[q]=r[q+1];
      r[19]=~0ULL;
    }
  }
}

__global__ void k_nbmax(const float* __restrict__ x, size_t BS, const int* __restrict__ idx,
                        float* __restrict__ nbm, int C){
  int t=blockIdx.x*256+threadIdx.x;
  if(t>=BB*C*NP)return;
  int n=t%NP; int bc=t/NP; int c=bc%C; int b=bc/C;
  const int* id=idx+((size_t)b*NP+n)*KK;
  const float* xr=x+(size_t)b*BS+(size_t)c*NP;
  float m=-FLT_MAX;
  for(int k=0;k<KK;k++) m=fmaxf(m,xr[id[k]]);
  nbm[t]=m;
}

// generic tiled GEMM: out[b][o][col] = WT^T @ B (+epilogue)
// EPI: 0 none, 1 relu, 2 add tensor, 3 bias per (b,o), 4 subtract tensor
template<int EPI>
__global__ __launch_bounds__(256) void k_gemm(
    const float* __restrict__ WT, int Os, int O, int Cin,
    const float* __restrict__ B1, size_t bs1, int split,
    const float* __restrict__ B2, size_t bs2,
    const float* __restrict__ ADD, size_t abs_,
    float* __restrict__ out, size_t obs, int ncols){
  __shared__ __align__(16) float At[16][64];
  __shared__ __align__(16) float Bt[16][64];
  int n0=blockIdx.x*64, o0=blockIdx.y*64, b=blockIdx.z;
  int tx=threadIdx.x%16, ty=threadIdx.x/16;
  float acc[4][4]={};
  for(int c0=0;c0<Cin;c0+=16){
    #pragma unroll
    for(int r=0;r<4;r++){
      int tl=threadIdx.x+256*r;
      int c=tl/64, e=tl%64;
      int cg=c0+c;
      At[c][e] = (cg<Cin && o0+e<O)? WT[(size_t)cg*Os + o0+e] : 0.f;
      float bv=0.f;
      if(cg<Cin){
        bv = (cg<split)? B1[(size_t)b*bs1 + (size_t)cg*ncols + n0+e]
                       : B2[(size_t)b*bs2 + (size_t)(cg-split)*ncols + n0+e];
      }
      Bt[c][e]=bv;
    }
    __syncthreads();
    int cm = (Cin-c0 < 16)? (Cin-c0) : 16;
    for(int c=0;c<cm;c++){
      float4 a4=*(const float4*)&At[c][ty*4];
      float4 b4=*(const float4*)&Bt[c][tx*4];
      float ar[4]={a4.x,a4.y,a4.z,a4.w}, br[4]={b4.x,b4.y,b4.z,b4.w};
      #pragma unroll
      for(int ii=0;ii<4;ii++)
        #pragma unroll
        for(int jj=0;jj<4;jj++) acc[ii][jj] += ar[ii]*br[jj];
    }
    __syncthreads();
  }
  #pragma unroll
  for(int ii=0;ii<4;ii++){
    int oo=o0+ty*4+ii;
    if(oo<O){
      #pragma unroll
      for(int jj=0;jj<4;jj++){
        int col=n0+tx*4+jj;
        float v=acc[ii][jj];
        if constexpr (EPI==2) v += ADD[(size_t)b*abs_ + (size_t)oo*ncols + col];
        if constexpr (EPI==4) v -= ADD[(size_t)b*abs_ + (size_t)oo*ncols + col];
        if constexpr (EPI==3) v += ADD[(size_t)b*abs_ + oo];
        if constexpr (EPI==1) v = fmaxf(v,0.f);
        out[(size_t)b*obs + (size_t)oo*ncols + col]=v;
      }
    }
  }
}

// Fused attention edge-conv:
// per k: quad-of-lanes-per-column computes channel softmax of leaky(P1T[id]+QT[n]),
// writes alpha*(xT[id]-xT[n]) straight into the LDS B-tile, then GEMM-accumulates
// Y = WecA @ EE + T3 and folds max/min/sum/ssq over k. EE never hits memory.
template<int C, int Cout>
__global__ __launch_bounds__(256) void k_fused(
    const float* __restrict__ xT,    // [b][NP][C]
    const float* __restrict__ p1T,   // [b][NP][C]
    const float* __restrict__ qT,    // [b][NP][C]
    const int* __restrict__ idx,     // [b][NP][KK]
    const float* __restrict__ wecAT, // [C][Cout]
    const float* __restrict__ T3,    // [b][Cout][NP]
    float* __restrict__ ymx, float* __restrict__ ymn,
    float* __restrict__ sumb, float* __restrict__ ssqb){
  constexpr int CHUNK = (C+3)/4;
  __shared__ __align__(16) float W[C][64];
  __shared__ __align__(16) float Bt[C][64];
  __shared__ int sid[64*KK];
  int n0=blockIdx.x*64, o0=blockIdx.y*64, b=blockIdx.z;
  int tid=threadIdx.x, tx=tid%16, ty=tid/16;
  int col=tid>>2, sub=tid&3;
  for(int t=tid;t<C*64;t+=256){
    int c=t/64, e=t%64;
    W[c][e]=wecAT[(size_t)c*Cout + o0+e];
  }
  for(int t=tid;t<64*KK;t+=256){
    sid[t]=idx[((size_t)b*NP + n0 + t/KK)*KK + (t%KK)];
  }
  const float* t3b=T3+(size_t)b*Cout*NP;
  float t3r[4][4];
  #pragma unroll
  for(int ii=0;ii<4;ii++)
    #pragma unroll
    for(int jj=0;jj<4;jj++)
      t3r[ii][jj]=t3b[(size_t)(o0+ty*4+ii)*NP + n0+tx*4+jj];
  float mx[4][4], mn[4][4], smr[4]={0,0,0,0}, ssr[4]={0,0,0,0};
  #pragma unroll
  for(int ii=0;ii<4;ii++)
    #pragma unroll
    for(int jj=0;jj<4;jj++){ mx[ii][jj]=-FLT_MAX; mn[ii][jj]=FLT_MAX; }
  const float* xb =xT +(size_t)b*NP*C;
  const float* pb =p1T+(size_t)b*NP*C;
  const float* qb =qT +(size_t)b*NP*C;
  int n=n0+col;
  const float* qrow =qb+(size_t)n*C;
  const float* xnrow=xb+(size_t)n*C;
  const int cb=sub*CHUNK;
  __syncthreads();
  for(int k=0;k<KK;k++){
    int id=sid[col*KK+k];
    const float* prow =pb+(size_t)id*C;
    const float* xirow=xb+(size_t)id*C;
    float a[CHUNK];
    float m=-FLT_MAX;
    #pragma unroll
    for(int j=0;j<CHUNK;j++){
      int c=cb+j;
      float v = (c<C)? prow[c]+qrow[c] : -FLT_MAX;
      v = v>0.f? v : NEGS*v;
      a[j]=v; m=fmaxf(m,v);
    }
    m=fmaxf(m,__shfl_xor(m,1,64));
    m=fmaxf(m,__shfl_xor(m,2,64));
    float s=0.f;
    #pragma unroll
    for(int j=0;j<CHUNK;j++){ float e=__expf(a[j]-m); a[j]=e; s+=e; }
    s+=__shfl_xor(s,1,64);
    s+=__shfl_xor(s,2,64);
    float rs=1.f/s;
    #pragma unroll
    for(int j=0;j<CHUNK;j++){
      int c=cb+j;
      if(c<C) Bt[c][col]=a[j]*rs*(xirow[c]-xnrow[c]);
    }
    __syncthreads();
    float acc[4][4]={};
    for(int c=0;c<C;c++){
      float4 w4=*(const float4*)&W[c][ty*4];
      float4 b4=*(const float4*)&Bt[c][tx*4];
      float wr[4]={w4.x,w4.y,w4.z,w4.w}, br[4]={b4.x,b4.y,b4.z,b4.w};
      #pragma unroll
      for(int ii=0;ii<4;ii++)
        #pragma unroll
        for(int jj=0;jj<4;jj++) acc[ii][jj]+=wr[ii]*br[jj];
    }
    #pragma unroll
    for(int ii=0;ii<4;ii++){
      float rsm=0.f, rss=0.f;
      #pragma unroll
      for(int jj=0;jj<4;jj++){
        float y=acc[ii][jj]+t3r[ii][jj];
        mx[ii][jj]=fmaxf(mx[ii][jj],y);
        mn[ii][jj]=fminf(mn[ii][jj],y);
        rsm+=y; rss+=y*y;
      }
      smr[ii]+=rsm; ssr[ii]+=rss;
    }
    __syncthreads();
  }
  #pragma unroll
  for(int ii=0;ii<4;ii++){
    int oo=o0+ty*4+ii;
    float4 v4; v4.x=mx[ii][0]; v4.y=mx[ii][1]; v4.z=mx[ii][2]; v4.w=mx[ii][3];
    *(float4*)&ymx[((size_t)b*Cout+oo)*NP + n0+tx*4] = v4;
    v4.x=mn[ii][0]; v4.y=mn[ii][1]; v4.z=mn[ii][2]; v4.w=mn[ii][3];
    *(float4*)&ymn[((size_t)b*Cout+oo)*NP + n0+tx*4] = v4;
  }
  #pragma unroll
  for(int off=1;off<16;off<<=1){
    #pragma unroll
    for(int ii=0;ii<4;ii++){
      smr[ii]+=__shfl_xor(smr[ii],off,64);
      ssr[ii]+=__shfl_xor(ssr[ii],off,64);
    }
  }
  if(tx==0){
    #pragma unroll
    for(int ii=0;ii<4;ii++){
      atomicAdd(&sumb[o0+ty*4+ii], smr[ii]);
      atomicAdd(&ssqb[o0+ty*4+ii], ssr[ii]);
    }
  }
}

__global__ void k_bnprep(const float* __restrict__ sumb, const float* __restrict__ ssqb,
                         const float* __restrict__ gg, const float* __restrict__ bb,
                         float* __restrict__ sct, int Cout, float invcnt){
  int o=blockIdx.x*256+threadIdx.x;
  if(o>=Cout)return;
  float m=sumb[o]*invcnt;
  float v=ssqb[o]*invcnt-m*m;
  float s=gg[o]*rsqrtf(v+BEPS);
  sct[o]=s; sct[Cout+o]=bb[o]-s*m;
}

__global__ void k_stageout(const float* __restrict__ ymaxb, const float* __restrict__ yminb,
                           const float* __restrict__ sct, float* __restrict__ xo, int Cout, size_t obs){
  int t=blockIdx.x*256+threadIdx.x;
  if(t>=BB*Cout*NP)return;
  int n=t%NP; int r=t/NP; int o=r%Cout; int b=r/Cout;
  float s=sct[o], tt=sct[Cout+o];
  float y = s>=0.f ? fmaf(s,ymaxb[t],tt) : fmaf(s,yminb[t],tt);
  xo[(size_t)b*obs + (size_t)o*NP + n]=fmaxf(y,0.f);
}

__global__ void k_stats(const float* __restrict__ y, const float* __restrict__ gg, const float* __restrict__ bb,
                        float* __restrict__ sct, int Cch){
  int o=blockIdx.x;
  float s=0.f, ss=0.f;
  for(int t=threadIdx.x;t<BB*NP;t+=256){
    int b=t/NP, n=t%NP;
    float v=y[((size_t)b*Cch+o)*NP+n];
    s+=v; ss+=v*v;
  }
  __shared__ float r1[256], r2[256];
  r1[threadIdx.x]=s; r2[threadIdx.x]=ss;
  __syncthreads();
  for(int st=128;st>0;st>>=1){
    if(threadIdx.x<st){ r1[threadIdx.x]+=r1[threadIdx.x+st]; r2[threadIdx.x]+=r2[threadIdx.x+st]; }
    __syncthreads();
  }
  if(threadIdx.x==0){
    float m=r1[0]/(float)(BB*NP);
    float v=r2[0]/(float)(BB*NP)-m*m;
    float sc=gg[o]*rsqrtf(v+BEPS);
    sct[o]=sc; sct[Cch+o]=bb[o]-sc*m;
  }
}

__global__ void k_gvec(const float* __restrict__ y, const float* __restrict__ sct,
                       float* __restrict__ gv, int Cch, int gstride){
  int blk=blockIdx.x; int b=blk/Cch, o=blk%Cch;
  float sc=sct[o], sh=sct[Cch+o];
  float m=-FLT_MAX;
  for(int n=threadIdx.x;n<NP;n+=256) m=fmaxf(m, fmaf(sc,y[((size_t)b*Cch+o)*NP+n],sh));
  __shared__ float r[256];
  r[threadIdx.x]=m; __syncthreads();
  for(int st=128;st>0;st>>=1){ if(threadIdx.x<st) r[threadIdx.x]=fmaxf(r[threadIdx.x],r[threadIdx.x+st]); __syncthreads(); }
  if(threadIdx.x==0) gv[(size_t)b*gstride+o]=fmaxf(r[0],0.f);
}

__global__ void k_t6(const float* __restrict__ gvec, const float* __restrict__ w6, float* __restrict__ t6b){
  int t=blockIdx.x*256+threadIdx.x;
  if(t>=BB*512)return;
  int b=t/512, o=t%512;
  const float* w=w6+(size_t)o*1152+128;
  const float* gv=gvec+(size_t)b*1024;
  float s=0.f;
  for(int c=0;c<1024;c++) s+=w[c]*gv[c];
  t6b[t]=s;
}

__global__ void k_norm(float* __restrict__ y, const float* __restrict__ sct, int Cch, int total){
  int t=blockIdx.x*256+threadIdx.x;
  if(t>=total)return;
  int o=(t/NP)%Cch;
  y[t]=fmaxf(fmaf(sct[o],y[t],sct[Cch+o]),0.f);
}

} // namespace

extern "C" void kernel_launch(void* const* d_in, const int* in_sizes, int n_in,
                              void* d_out, int out_size, void* d_ws, size_t ws_size,
                              hipStream_t stream){
  const float* x   =(const float*)d_in[0];
  const float* wa_1[4]={(const float*)d_in[1],(const float*)d_in[3],(const float*)d_in[5],(const float*)d_in[7]};
  const float* wa_2[4]={(const float*)d_in[2],(const float*)d_in[4],(const float*)d_in[6],(const float*)d_in[8]};
  const float* wfn[4]={(const float*)d_in[9],(const float*)d_in[10],(const float*)d_in[11],(const float*)d_in[12]};
  const float* wec[4]={(const float*)d_in[13],(const float*)d_in[14],(const float*)d_in[15],(const float*)d_in[16]};
  const float* w5=(const float*)d_in[17];
  const float* w6=(const float*)d_in[18];
  const float* w7=(const float*)d_in[19];
  const float* w8=(const float*)d_in[20];
  const float* gs[7]; const float* bs[7];
  for(int i=0;i<7;i++){ gs[i]=(const float*)d_in[21+2*i]; bs[i]=(const float*)d_in[22+2*i]; }

  const int Cs[4]={10,64,64,128};
  const int Co[4]={64,64,128,256};
  const size_t U=(size_t)BB*NP;

  float* base=(float*)d_ws;
  size_t off=0;
  auto alloc=[&](size_t nfl)->float*{ float* p=base+off; off+=(nfl+3)&~(size_t)3; return p; };

  // fixed buffers
  float* f_buf = alloc(10*U);
  float* xcat  = alloc(512*U);
  float* sq    = alloc(U);
  int*   idxb  = (int*)alloc(20*U);
  float* Qb    = alloc(128*U);      // Q = Wa2.x - P1   [C][NP]
  float* P1b   = alloc(128*U);      // P1 = Wa1.x       [C][NP]
  float* xTb   = alloc(128*U);      // [n][C]
  float* p1Tb  = alloc(128*U);
  float* qTb   = alloc(128*U);
  float* R2    = alloc(256*U);      // nbm then T3
  float* ymx   = alloc(256*U);
  float* ymn   = alloc(256*U);
  float* sums  = alloc(2048);
  float* sct   = alloc(4096);
  float* gvecb = alloc(4096);
  float* t6b   = alloc(2048);
  float* meanxb= alloc(16);
  // transposed weights
  float* wa1T[4]; float* wa2T[4]; float* wecAT[4]; float* wecBT[4]; float* wecGT[4]; float* wfnT[4];
  for(int s=0;s<4;s++){
    int C=Cs[s], Cout=Co[s];
    wa1T[s]=alloc((size_t)C*C); wa2T[s]=alloc((size_t)C*C);
    wecAT[s]=alloc((size_t)C*Cout); wecBT[s]=alloc((size_t)C*Cout);
    wecGT[s]=alloc((size_t)512*Cout); wfnT[s]=alloc((size_t)2*C*512);
  }
  float* w5T=alloc((size_t)512*1024); float* w6mT=alloc((size_t)128*512);
  float* w7T=alloc((size_t)512*256);  float* w8T=alloc((size_t)256*50);

  // R1 region: Dbuf (512U) / gfb (512U) / y5h (512U) / y6+y7 (768U)
  float* R1 = alloc(768*U);
  float* Dbuf=R1; float* gfb=R1;
  float* y5h=R1; float* y6=R1; float* y7=R1+512*U;
  float* nbm=R2; float* T3=R2;
  (void)ws_size;

  hipMemsetAsync(sums,0,2048*sizeof(float),stream);

  for(int s=0;s<4;s++){
    int C=Cs[s], Cout=Co[s], Cin=2*C+512;
    k_transpose<<<(C*C+255)/256,256,0,stream>>>(wa_1[s],wa1T[s],C,C,C,0);
    k_transpose<<<(C*C+255)/256,256,0,stream>>>(wa_2[s],wa2T[s],C,C,C,0);
    k_transpose<<<(C*Cout+255)/256,256,0,stream>>>(wec[s],wecAT[s],Cout,C,Cin,0);
    k_transpose<<<(C*Cout+255)/256,256,0,stream>>>(wec[s],wecBT[s],Cout,C,Cin,C);
    k_transpose<<<(512*Cout+255)/256,256,0,stream>>>(wec[s],wecGT[s],Cout,512,Cin,2*C);
    k_transpose<<<(2*C*512+255)/256,256,0,stream>>>(wfn[s],wfnT[s],512,2*C,2*C,0);
  }
  k_transpose<<<(512*1024+255)/256,256,0,stream>>>(w5,w5T,1024,512,512,0);
  k_transpose<<<(128*512+255)/256,256,0,stream>>>(w6,w6mT,512,128,1152,0);
  k_transpose<<<(512*256+255)/256,256,0,stream>>>(w7,w7T,256,512,512,0);
  k_transpose<<<(256*50+255)/256,256,0,stream>>>(w8,w8T,50,256,256,0);

  k_meanx<<<12,256,0,stream>>>(x,meanxb);
  k_repsurf<<<(BB*NP+255)/256,256,0,stream>>>(x,meanxb,f_buf);

  const float* xin[4]={f_buf, xcat, xcat+(size_t)64*NP, xcat+(size_t)128*NP};
  const size_t BSs[4]={(size_t)10*NP,(size_t)512*NP,(size_t)512*NP,(size_t)512*NP};
  float* xoutb[4]={xcat, xcat+(size_t)64*NP, xcat+(size_t)128*NP, xcat+(size_t)256*NP};

  for(int s=0;s<4;s++){
    int C=Cs[s], Cout=Co[s];
    size_t BS=BSs[s];
    k_sqnorm<<<(int)((U+255)/256),256,0,stream>>>(xin[s],BS,sq,C);
    for(int b=0;b<BB;b++){
      k_dist<<<dim3(NP/128,NP/128),256,0,stream>>>(xin[s]+(size_t)b*BS, sq+(size_t)b*NP, Dbuf, C);
      k_topk<<<NP/4,256,0,stream>>>(Dbuf, idxb+(size_t)b*NP*KK);
    }
    k_nbmax<<<(int)((BB*(size_t)C*NP+255)/256),256,0,stream>>>(xin[s],BS,idxb,nbm,C);
    // gf = relu(Wfn @ [x; nbmax])
    k_gemm<1><<<dim3(32,8,BB),256,0,stream>>>(wfnT[s],512,512,2*C, xin[s],BS,C, nbm,(size_t)C*NP,
                                              nullptr,0, gfb,(size_t)512*NP, NP);
    // T3 = WecG @ gf ; then T3 += WecB @ x (in place)
    k_gemm<0><<<dim3(32,Cout/64,BB),256,0,stream>>>(wecGT[s],Cout,Cout,512, gfb,(size_t)512*NP,512,
                                              nullptr,0, nullptr,0, T3,(size_t)Cout*NP, NP);
    k_gemm<2><<<dim3(32,Cout/64,BB),256,0,stream>>>(wecBT[s],Cout,Cout,C, xin[s],BS,C,
                                              nullptr,0, T3,(size_t)Cout*NP, T3,(size_t)Cout*NP, NP);
    // P1 = Wa1 @ x ; Q = Wa2 @ x - P1
    k_gemm<0><<<dim3(32,(C+63)/64,BB),256,0,stream>>>(wa1T[s],C,C,C, xin[s],BS,C,
                                              nullptr,0, nullptr,0, P1b,(size_t)C*NP, NP);
    k_gemm<4><<<dim3(32,(C+63)/64,BB),256,0,stream>>>(wa2T[s],C,C,C, xin[s],BS,C,
                                              nullptr,0, P1b,(size_t)C*NP, Qb,(size_t)C*NP, NP);
    // point-major transposes
    k_trT<<<dim3(NP/32,(C+31)/32,BB),256,0,stream>>>(xin[s],BS,xTb,C);
    k_trT<<<dim3(NP/32,(C+31)/32,BB),256,0,stream>>>(P1b,(size_t)C*NP,p1Tb,C);
    k_trT<<<dim3(NP/32,(C+31)/32,BB),256,0,stream>>>(Qb,(size_t)C*NP,qTb,C);
    float* sb=sums+(size_t)s*512; float* qb=sb+256;
    if(s==0)      k_fused<10,64  ><<<dim3(NP/64,1,BB),256,0,stream>>>(xTb,p1Tb,qTb,idxb,wecAT[s],T3,ymx,ymn,sb,qb);
    else if(s==1) k_fused<64,64  ><<<dim3(NP/64,1,BB),256,0,stream>>>(xTb,p1Tb,qTb,idxb,wecAT[s],T3,ymx,ymn,sb,qb);
    else if(s==2) k_fused<64,128 ><<<dim3(NP/64,2,BB),256,0,stream>>>(xTb,p1Tb,qTb,idxb,wecAT[s],T3,ymx,ymn,sb,qb);
    else          k_fused<128,256><<<dim3(NP/64,4,BB),256,0,stream>>>(xTb,p1Tb,qTb,idxb,wecAT[s],T3,ymx,ymn,sb,qb);
    k_bnprep<<<1,256,0,stream>>>(sb,qb,gs[s],bs[s],sct,Cout,1.f/(float)((size_t)BB*NP*KK));
    k_stageout<<<(int)((BB*(size_t)Cout*NP+255)/256),256,0,stream>>>(ymx,ymn,sct,xoutb[s],Cout,(size_t)512*NP);
  }

  // head: y5 in two 512-channel halves
  for(int h=0;h<2;h++){
    k_gemm<0><<<dim3(32,8,BB),256,0,stream>>>(w5T+(size_t)h*512,1024,512,512, xcat,(size_t)512*NP,512,
                                              nullptr,0, nullptr,0, y5h,(size_t)512*NP, NP);
    k_stats<<<512,256,0,stream>>>(y5h,gs[4]+h*512,bs[4]+h*512,sct,512);
    k_gvec<<<BB*512,256,0,stream>>>(y5h,sct,gvecb+h*512,512,1024);
  }
  k_t6<<<(BB*512+255)/256,256,0,stream>>>(gvecb,w6,t6b);
  k_gemm<3><<<dim3(32,8,BB),256,0,stream>>>(w6mT,512,512,128, xcat+(size_t)128*NP,(size_t)512*NP,128,
                                            nullptr,0, t6b,512, y6,(size_t)512*NP, NP);
  k_stats<<<512,256,0,stream>>>(y6,gs[5],bs[5],sct,512);
  k_norm<<<(int)((BB*(size_t)512*NP+255)/256),256,0,stream>>>(y6,sct,512,(int)(BB*512*NP));
  k_gemm<0><<<dim3(32,4,BB),256,0,stream>>>(w7T,256,256,512, y6,(size_t)512*NP,512,
                                            nullptr,0, nullptr,0, y7,(size_t)256*NP, NP);
  k_stats<<<256,256,0,stream>>>(y7,gs[6],bs[6],sct,256);
  k_norm<<<(int)((BB*(size_t)256*NP+255)/256),256,0,stream>>>(y7,sct,256,(int)(BB*256*NP));
  k_gemm<1><<<dim3(32,1,BB),256,0,stream>>>(w8T,50,50,256, y7,(size_t)256*NP,256,
                                            nullptr,0, nullptr,0, (float*)d_out,(size_t)50*NP, NP);

  (void)in_sizes; (void)n_in; (void)out_size;
}

// Round 10
// 2624.103 us; speedup vs baseline: 2.0726x; 1.1420x over previous
//
#include <hip/hip_runtime.h>
#include <float.h>
#include <math.h>

namespace {

constexpr int BB = 4;
constexpr int NP = 2048;
constexpr int KK = 20;
constexpr float NEGS = 0.2f;
constexpr float BEPS = 1e-5f;

__global__ void k_meanx(const float* __restrict__ x, float* __restrict__ meanx){
  int bc = blockIdx.x;
  const float* p = x + (size_t)bc*NP;
  float s=0.f;
  for(int n=threadIdx.x;n<NP;n+=256) s+=p[n];
  __shared__ float red[256];
  red[threadIdx.x]=s; __syncthreads();
  for(int st=128;st>0;st>>=1){ if(threadIdx.x<st) red[threadIdx.x]+=red[threadIdx.x+st]; __syncthreads(); }
  if(threadIdx.x==0) meanx[bc]=red[0]/(float)NP;
}

__global__ void k_repsurf(const float* __restrict__ x, const float* __restrict__ meanx, float* __restrict__ f){
  int t=blockIdx.x*256+threadIdx.x;
  if(t>=BB*NP) return;
  int b=t/NP, n=t%NP;
  float p0=x[(b*3+0)*NP+n], p1=x[(b*3+1)*NP+n], p2=x[(b*3+2)*NP+n];
  float c0=p0-meanx[b*3+0], c1=p1-meanx[b*3+1], c2=p2-meanx[b*3+2];
  float r=sqrtf(p0*p0+p1*p1+p2*p2);
  float* fb=f+(size_t)b*10*NP+n;
  fb[0]=p0; fb[NP]=p1; fb[2*NP]=p2;
  fb[3*NP]=c0; fb[4*NP]=c1; fb[5*NP]=c2;
  fb[6*NP]=p0*p0; fb[7*NP]=p1*p1; fb[8*NP]=p2*p2;
  fb[9*NP]=r;
}

// out[s*OS + opos + r] = in[r*rs + off + s]
__global__ void k_transpose(const float* __restrict__ in, float* __restrict__ out,
                            int R, int S, int rs, int off, int OS, int opos){
  int t=blockIdx.x*256+threadIdx.x;
  if(t>=R*S) return;
  int s=t/R, r=t%R;
  out[(size_t)s*OS + opos + r] = in[(size_t)r*rs + off + s];
}

// tiled activation transpose: in [b][C][NP] (batch stride BS) -> out [b][NP][C]
__global__ __launch_bounds__(256) void k_trT(const float* __restrict__ in, size_t BS,
                                             float* __restrict__ out, int C){
  __shared__ float t[32][33];
  int n0=blockIdx.x*32, c0=blockIdx.y*32, b=blockIdx.z;
  int tx=threadIdx.x%32, ty=threadIdx.x/32;
  #pragma unroll
  for(int r=0;r<32;r+=8){
    int c=c0+ty+r;
    t[ty+r][tx] = (c<C)? in[(size_t)b*BS + (size_t)c*NP + n0+tx] : 0.f;
  }
  __syncthreads();
  #pragma unroll
  for(int r=0;r<32;r+=8){
    int n=n0+ty+r, c=c0+tx;
    if(c<C) out[((size_t)b*NP + n)*C + c] = t[tx][ty+r];
  }
}

__global__ void k_sqnorm(const float* __restrict__ x, size_t BS, float* __restrict__ sq, int C){
  int t=blockIdx.x*256+threadIdx.x;
  if(t>=BB*NP)return;
  int b=t/NP, n=t%NP;
  const float* xb=x+(size_t)b*BS+n;
  float s=0.f;
  for(int c=0;c<C;c++){ float v=xb[(size_t)c*NP]; s+=v*v; }
  sq[t]=s;
}

// 128x128 tile, 8x8 micro distance GEMM; blockIdx.z = batch
__global__ __launch_bounds__(256) void k_dist(const float* __restrict__ x, size_t BS,
                                              const float* __restrict__ sq,
                                              float* __restrict__ D, size_t Dstr, int C){
  __shared__ __align__(16) float At[16][128];
  __shared__ __align__(16) float Bt[16][128];
  int bz=blockIdx.z;
  const float* xb=x+(size_t)bz*BS;
  const float* sqb=sq+(size_t)bz*NP;
  float* Db=D+(size_t)bz*Dstr;
  int j0 = blockIdx.x*128, i0 = blockIdx.y*128;
  int tx = threadIdx.x%16, ty = threadIdx.x/16;
  float acc[8][8]={};
  for(int c0=0;c0<C;c0+=16){
    #pragma unroll
    for(int r=0;r<8;r++){
      int tl = threadIdx.x + 256*r;
      int c = tl>>7, e = tl&127;
      int cg = c0+c;
      At[c][e] = (cg<C)? xb[(size_t)cg*NP + i0 + e] : 0.f;
    }
    #pragma unroll
    for(int r=0;r<8;r++){
      int tl = threadIdx.x + 256*r;
      int c = tl>>7, e = tl&127;
      int cg = c0+c;
      Bt[c][e] = (cg<C)? xb[(size_t)cg*NP + j0 + e] : 0.f;
    }
    __syncthreads();
    int cm = (C-c0 < 16)? (C-c0) : 16;
    for(int c=0;c<cm;c++){
      float4 a0=*(const float4*)&At[c][ty*8];
      float4 a1=*(const float4*)&At[c][ty*8+4];
      float4 b0=*(const float4*)&Bt[c][tx*8];
      float4 b1=*(const float4*)&Bt[c][tx*8+4];
      float ar[8]={a0.x,a0.y,a0.z,a0.w,a1.x,a1.y,a1.z,a1.w};
      float br[8]={b0.x,b0.y,b0.z,b0.w,b1.x,b1.y,b1.z,b1.w};
      #pragma unroll
      for(int ii=0;ii<8;ii++)
        #pragma unroll
        for(int jj=0;jj<8;jj++) acc[ii][jj] += ar[ii]*br[jj];
    }
    __syncthreads();
  }
  #pragma unroll
  for(int ii=0;ii<8;ii++){
    int i=i0+ty*8+ii;
    float si=sqb[i];
    #pragma unroll
    for(int jq=0;jq<2;jq++){
      int j=j0+tx*8+jq*4;
      float4 w;
      w.x = si + sqb[j+0] - 2.f*acc[ii][jq*4+0];
      w.y = si + sqb[j+1] - 2.f*acc[ii][jq*4+1];
      w.z = si + sqb[j+2] - 2.f*acc[ii][jq*4+2];
      w.w = si + sqb[j+3] - 2.f*acc[ii][jq*4+3];
      *(float4*)&Db[(size_t)i*NP + j] = w;
    }
  }
}

__global__ __launch_bounds__(256) void k_topk(const float* __restrict__ D, size_t Dstr,
                                              int* __restrict__ out){
  int bz=blockIdx.z;
  int wid = threadIdx.x>>6, lane = threadIdx.x&63;
  int row = blockIdx.x*4 + wid;
  const float* d = D + (size_t)bz*Dstr + (size_t)row*NP;
  unsigned long long r[20];
  #pragma unroll
  for(int q=0;q<20;q++) r[q]=~0ULL;
  for(int t=0;t<NP/64;t++){
    int j = lane + 64*t;
    float v = d[j];
    unsigned u = __float_as_uint(v);
    u = (u & 0x80000000u) ? ~u : (u | 0x80000000u);
    unsigned long long key = ((unsigned long long)u<<32) | (unsigned)j;
    if(key < r[19]){
      #pragma unroll
      for(int q=0;q<20;q++){
        unsigned long long lo = key<r[q]?key:r[q];
        unsigned long long hi = key<r[q]?r[q]:key;
        r[q]=lo; key=hi;
      }
    }
  }
  int* o = out + (size_t)bz*NP*KK + (size_t)row*KK;
  for(int kk=0;kk<KK;kk++){
    unsigned long long m = r[0];
    #pragma unroll
    for(int off=1;off<64;off<<=1){
      unsigned long long ot = __shfl_xor(m, off, 64);
      if(ot<m) m=ot;
    }
    if(lane==0) o[kk] = (int)(unsigned)(m & 0xffffffffULL);
    if(r[0]==m){
      #pragma unroll
      for(int q=0;q<19;q++) r[q]=r[q+1];
      r[19]=~0ULL;
    }
  }
}

__global__ void k_nbmax(const float* __restrict__ x, size_t BS, const int* __restrict__ idx,
                        float* __restrict__ nbm, int C){
  int t=blockIdx.x*256+threadIdx.x;
  if(t>=BB*C*NP)return;
  int n=t%NP; int bc=t/NP; int c=bc%C; int b=bc/C;
  const int* id=idx+((size_t)b*NP+n)*KK;
  const float* xr=x+(size_t)b*BS+(size_t)c*NP;
  float m=-FLT_MAX;
  for(int k=0;k<KK;k++) m=fmaxf(m,xr[id[k]]);
  nbm[t]=m;
}

// 64x64 tile, 4x4 micro GEMM.
// EPI: 0 none, 1 relu, 3 bias addv[b][O], 5 transposed dual write (out/out2 split at Chalf)
template<int EPI, bool INNORM>
__global__ __launch_bounds__(256) void k_g64(
    const float* __restrict__ WT, int Os, int O, int Cin,
    const float* __restrict__ B1, size_t bs1, int split,
    const float* __restrict__ B2, size_t bs2,
    const float* __restrict__ addv, size_t avs,
    const float* __restrict__ sct, int sctC,
    float* __restrict__ out, size_t obs, int ncols,
    float* __restrict__ out2, int Chalf){
  __shared__ __align__(16) float At[16][64];
  __shared__ __align__(16) float Bt[16][64];
  int n0=blockIdx.x*64, o0=blockIdx.y*64, b=blockIdx.z;
  int tx=threadIdx.x%16, ty=threadIdx.x/16;
  float acc[4][4]={};
  for(int c0=0;c0<Cin;c0+=16){
    #pragma unroll
    for(int r=0;r<4;r++){
      int tl=threadIdx.x+256*r;
      int c=tl/64, e=tl%64;
      int cg=c0+c;
      At[c][e] = (cg<Cin && o0+e<O)? WT[(size_t)cg*Os + o0+e] : 0.f;
      float bv=0.f;
      if(cg<Cin){
        bv = (cg<split)? B1[(size_t)b*bs1 + (size_t)cg*ncols + n0+e]
                       : B2[(size_t)b*bs2 + (size_t)(cg-split)*ncols + n0+e];
        if(INNORM) bv = fmaxf(fmaf(sct[cg],bv,sct[sctC+cg]),0.f);
      }
      Bt[c][e]=bv;
    }
    __syncthreads();
    int cm = (Cin-c0 < 16)? (Cin-c0) : 16;
    for(int c=0;c<cm;c++){
      float4 a4=*(const float4*)&At[c][ty*4];
      float4 b4=*(const float4*)&Bt[c][tx*4];
      float ar[4]={a4.x,a4.y,a4.z,a4.w}, br[4]={b4.x,b4.y,b4.z,b4.w};
      #pragma unroll
      for(int ii=0;ii<4;ii++)
        #pragma unroll
        for(int jj=0;jj<4;jj++) acc[ii][jj] += ar[ii]*br[jj];
    }
    __syncthreads();
  }
  #pragma unroll
  for(int ii=0;ii<4;ii++){
    int oo=o0+ty*4+ii;
    if(oo<O){
      if constexpr (EPI==5){
        #pragma unroll
        for(int jj=0;jj<4;jj++){
          int col=n0+tx*4+jj;
          float v=acc[ii][jj];
          if(oo<Chalf) out [((size_t)b*ncols+col)*Chalf + oo]       = v;
          else         out2[((size_t)b*ncols+col)*Chalf + oo-Chalf] = v;
        }
      } else {
        float bia = (EPI==3)? addv[(size_t)b*avs + oo] : 0.f;
        #pragma unroll
        for(int jj=0;jj<4;jj++){
          int col=n0+tx*4+jj;
          float v=acc[ii][jj]+bia;
          if(EPI==1) v=fmaxf(v,0.f);
          out[(size_t)b*obs + (size_t)oo*ncols + col]=v;
        }
      }
    }
  }
}

// 128x128 tile, 8x8 micro GEMM. EPI: 0 none, 1 relu, 3 bias
template<int EPI, bool INNORM>
__global__ __launch_bounds__(256) void k_g128(
    const float* __restrict__ WT, int Os, int O, int Cin,
    const float* __restrict__ B1, size_t bs1, int split,
    const float* __restrict__ B2, size_t bs2,
    const float* __restrict__ addv, size_t avs,
    const float* __restrict__ sct, int sctC,
    float* __restrict__ out, size_t obs, int ncols){
  __shared__ __align__(16) float At[16][128];
  __shared__ __align__(16) float Bt[16][128];
  int n0=blockIdx.x*128, o0=blockIdx.y*128, b=blockIdx.z;
  int tx=threadIdx.x%16, ty=threadIdx.x/16;
  float acc[8][8]={};
  for(int c0=0;c0<Cin;c0+=16){
    #pragma unroll
    for(int r=0;r<8;r++){
      int tl=threadIdx.x+256*r;
      int c=tl>>7, e=tl&127;
      int cg=c0+c;
      At[c][e] = (cg<Cin && o0+e<O)? WT[(size_t)cg*Os + o0+e] : 0.f;
    }
    #pragma unroll
    for(int r=0;r<8;r++){
      int tl=threadIdx.x+256*r;
      int c=tl>>7, e=tl&127;
      int cg=c0+c;
      float bv=0.f;
      if(cg<Cin){
        bv = (cg<split)? B1[(size_t)b*bs1 + (size_t)cg*ncols + n0+e]
                       : B2[(size_t)b*bs2 + (size_t)(cg-split)*ncols + n0+e];
        if(INNORM) bv = fmaxf(fmaf(sct[cg],bv,sct[sctC+cg]),0.f);
      }
      Bt[c][e]=bv;
    }
    __syncthreads();
    int cm = (Cin-c0 < 16)? (Cin-c0) : 16;
    for(int c=0;c<cm;c++){
      float4 a0=*(const float4*)&At[c][ty*8];
      float4 a1=*(const float4*)&At[c][ty*8+4];
      float4 b0=*(const float4*)&Bt[c][tx*8];
      float4 b1=*(const float4*)&Bt[c][tx*8+4];
      float ar[8]={a0.x,a0.y,a0.z,a0.w,a1.x,a1.y,a1.z,a1.w};
      float br[8]={b0.x,b0.y,b0.z,b0.w,b1.x,b1.y,b1.z,b1.w};
      #pragma unroll
      for(int ii=0;ii<8;ii++)
        #pragma unroll
        for(int jj=0;jj<8;jj++) acc[ii][jj] += ar[ii]*br[jj];
    }
    __syncthreads();
  }
  #pragma unroll
  for(int ii=0;ii<8;ii++){
    int oo=o0+ty*8+ii;
    if(oo<O){
      float bia = (EPI==3)? addv[(size_t)b*avs + oo] : 0.f;
      #pragma unroll
      for(int jj=0;jj<8;jj++){
        int col=n0+tx*8+jj;
        float v=acc[ii][jj]+bia;
        if(EPI==1) v=fmaxf(v,0.f);
        out[(size_t)b*obs + (size_t)oo*ncols + col]=v;
      }
    }
  }
}

// Fused attention edge-conv. Channel-interleaved quads (c = sub + 4j), Bt stride 68
// (conflict-free writes). q and x_n rows preloaded (k-invariant). EE never in memory.
template<int C, int Cout>
__global__ __launch_bounds__(256) void k_fused(
    const float* __restrict__ xT, const float* __restrict__ p1T, const float* __restrict__ a2T,
    const int* __restrict__ idx, const float* __restrict__ wecAT, const float* __restrict__ T3,
    float* __restrict__ ymx, float* __restrict__ ymn,
    float* __restrict__ sumb, float* __restrict__ ssqb){
  constexpr int CHUNK=(C+3)/4;
  __shared__ __align__(16) float W[C][64];
  __shared__ __align__(16) float Bt[C][68];
  __shared__ int sid[64*KK];
  int n0=blockIdx.x*64, o0=blockIdx.y*64, b=blockIdx.z;
  int tid=threadIdx.x, tx=tid%16, ty=tid/16;
  int col=tid>>2, sub=tid&3;
  for(int t=tid;t<C*64;t+=256){
    int c=t/64, e=t%64;
    W[c][e]=wecAT[(size_t)c*Cout + o0+e];
  }
  for(int t=tid;t<64*KK;t+=256)
    sid[t]=idx[((size_t)b*NP + n0 + t/KK)*KK + (t%KK)];
  const float* t3b=T3+(size_t)b*Cout*NP;
  float t3r[4][4];
  #pragma unroll
  for(int ii=0;ii<4;ii++)
    #pragma unroll
    for(int jj=0;jj<4;jj++)
      t3r[ii][jj]=t3b[(size_t)(o0+ty*4+ii)*NP + n0+tx*4+jj];
  int n=n0+col;
  const float* xnrow=xT +((size_t)b*NP+n)*C;
  const float* p1n  =p1T+((size_t)b*NP+n)*C;
  const float* a2n  =a2T+((size_t)b*NP+n)*C;
  float qv[CHUNK], xnv[CHUNK];
  #pragma unroll
  for(int j=0;j<CHUNK;j++){
    int c=sub+4*j;
    qv[j]  = (c<C)? a2n[c]-p1n[c] : 0.f;
    xnv[j] = (c<C)? xnrow[c] : 0.f;
  }
  float mx[4][4], mn[4][4], smr[4]={0,0,0,0}, ssr[4]={0,0,0,0};
  #pragma unroll
  for(int ii=0;ii<4;ii++)
    #pragma unroll
    for(int jj=0;jj<4;jj++){ mx[ii][jj]=-FLT_MAX; mn[ii][jj]=FLT_MAX; }
  __syncthreads();
  for(int k=0;k<KK;k++){
    int id=sid[col*KK+k];
    const float* prow =p1T+((size_t)b*NP+id)*C;
    const float* xirow=xT +((size_t)b*NP+id)*C;
    float a[CHUNK];
    float m=-FLT_MAX;
    #pragma unroll
    for(int j=0;j<CHUNK;j++){
      int c=sub+4*j;
      float v = (c<C)? prow[c]+qv[j] : -FLT_MAX;
      v = v>0.f? v : NEGS*v;
      a[j]=v; m=fmaxf(m,v);
    }
    m=fmaxf(m,__shfl_xor(m,1,64));
    m=fmaxf(m,__shfl_xor(m,2,64));
    float s=0.f;
    #pragma unroll
    for(int j=0;j<CHUNK;j++){ float e=__expf(a[j]-m); a[j]=e; s+=e; }
    s+=__shfl_xor(s,1,64);
    s+=__shfl_xor(s,2,64);
    float rs=1.f/s;
    #pragma unroll
    for(int j=0;j<CHUNK;j++){
      int c=sub+4*j;
      if(c<C) Bt[c][col]=a[j]*rs*(xirow[c]-xnv[j]);
    }
    __syncthreads();
    float acc[4][4]={};
    for(int c=0;c<C;c++){
      float4 w4=*(const float4*)&W[c][ty*4];
      float4 b4=*(const float4*)&Bt[c][tx*4];
      float wr[4]={w4.x,w4.y,w4.z,w4.w}, br[4]={b4.x,b4.y,b4.z,b4.w};
      #pragma unroll
      for(int ii=0;ii<4;ii++)
        #pragma unroll
        for(int jj=0;jj<4;jj++) acc[ii][jj]+=wr[ii]*br[jj];
    }
    #pragma unroll
    for(int ii=0;ii<4;ii++){
      float rsm=0.f, rss=0.f;
      #pragma unroll
      for(int jj=0;jj<4;jj++){
        float y=acc[ii][jj]+t3r[ii][jj];
        mx[ii][jj]=fmaxf(mx[ii][jj],y);
        mn[ii][jj]=fminf(mn[ii][jj],y);
        rsm+=y; rss+=y*y;
      }
      smr[ii]+=rsm; ssr[ii]+=rss;
    }
    __syncthreads();
  }
  #pragma unroll
  for(int ii=0;ii<4;ii++){
    int oo=o0+ty*4+ii;
    float4 v4; v4.x=mx[ii][0]; v4.y=mx[ii][1]; v4.z=mx[ii][2]; v4.w=mx[ii][3];
    *(float4*)&ymx[((size_t)b*Cout+oo)*NP + n0+tx*4] = v4;
    v4.x=mn[ii][0]; v4.y=mn[ii][1]; v4.z=mn[ii][2]; v4.w=mn[ii][3];
    *(float4*)&ymn[((size_t)b*Cout+oo)*NP + n0+tx*4] = v4;
  }
  #pragma unroll
  for(int off=1;off<16;off<<=1){
    #pragma unroll
    for(int ii=0;ii<4;ii++){
      smr[ii]+=__shfl_xor(smr[ii],off,64);
      ssr[ii]+=__shfl_xor(ssr[ii],off,64);
    }
  }
  if(tx==0){
    #pragma unroll
    for(int ii=0;ii<4;ii++){
      atomicAdd(&sumb[o0+ty*4+ii], smr[ii]);
      atomicAdd(&ssqb[o0+ty*4+ii], ssr[ii]);
    }
  }
}

// BN-prep inline + BN-max/min trick + relu; dual write: x (col-major) and xT (row-major)
__global__ __launch_bounds__(256) void k_stageoutT(
    const float* __restrict__ ymx, const float* __restrict__ ymn,
    const float* __restrict__ sumb, const float* __restrict__ ssqb,
    const float* __restrict__ gg, const float* __restrict__ bb, float invcnt,
    float* __restrict__ xo, size_t obs, float* __restrict__ xT, int Cout, int writeT){
  __shared__ float t[32][33];
  int n0=blockIdx.x*32, o0=blockIdx.y*32, b=blockIdx.z;
  int tx=threadIdx.x%32, ty=threadIdx.x/32;
  #pragma unroll
  for(int r=0;r<32;r+=8){
    int o=o0+ty+r;
    float m=sumb[o]*invcnt;
    float v=ssqb[o]*invcnt-m*m;
    float sc=gg[o]*rsqrtf(v+BEPS);
    float sh=bb[o]-sc*m;
    size_t base=((size_t)b*Cout+o)*NP + n0+tx;
    float y = sc>=0.f ? fmaf(sc,ymx[base],sh) : fmaf(sc,ymn[base],sh);
    y=fmaxf(y,0.f);
    xo[(size_t)b*obs + (size_t)o*NP + n0+tx] = y;
    t[ty+r][tx]=y;
  }
  if(writeT){
    __syncthreads();
    #pragma unroll
    for(int r=0;r<32;r+=8){
      int n=n0+ty+r;
      xT[((size_t)b*NP+n)*Cout + o0+tx] = t[tx][ty+r];
    }
  }
}

__global__ void k_stats(const float* __restrict__ y, const float* __restrict__ gg, const float* __restrict__ bb,
                        float* __restrict__ sct, int Cch){
  int o=blockIdx.x;
  float s=0.f, ss=0.f;
  for(int t=threadIdx.x;t<BB*NP;t+=256){
    int b=t/NP, n=t%NP;
    float v=y[((size_t)b*Cch+o)*NP+n];
    s+=v; ss+=v*v;
  }
  __shared__ float r1[256], r2[256];
  r1[threadIdx.x]=s; r2[threadIdx.x]=ss;
  __syncthreads();
  for(int st=128;st>0;st>>=1){
    if(threadIdx.x<st){ r1[threadIdx.x]+=r1[threadIdx.x+st]; r2[threadIdx.x]+=r2[threadIdx.x+st]; }
    __syncthreads();
  }
  if(threadIdx.x==0){
    float m=r1[0]/(float)(BB*NP);
    float v=r2[0]/(float)(BB*NP)-m*m;
    float sc=gg[o]*rsqrtf(v+BEPS);
    sct[o]=sc; sct[Cch+o]=bb[o]-sc*m;
  }
}

__global__ void k_gvec(const float* __restrict__ y, const float* __restrict__ sct,
                       float* __restrict__ gv, int Cch, int gstride){
  int blk=blockIdx.x; int b=blk/Cch, o=blk%Cch;
  float sc=sct[o], sh=sct[Cch+o];
  float m=-FLT_MAX;
  for(int n=threadIdx.x;n<NP;n+=256) m=fmaxf(m, fmaf(sc,y[((size_t)b*Cch+o)*NP+n],sh));
  __shared__ float r[256];
  r[threadIdx.x]=m; __syncthreads();
  for(int st=128;st>0;st>>=1){ if(threadIdx.x<st) r[threadIdx.x]=fmaxf(r[threadIdx.x],r[threadIdx.x+st]); __syncthreads(); }
  if(threadIdx.x==0) gv[(size_t)b*gstride+o]=fmaxf(r[0],0.f);
}

__global__ void k_t6(const float* __restrict__ gvec, const float* __restrict__ w6, float* __restrict__ t6b){
  int t=blockIdx.x*256+threadIdx.x;
  if(t>=BB*512)return;
  int b=t/512, o=t%512;
  const float* w=w6+(size_t)o*1152+128;
  const float* gv=gvec+(size_t)b*1024;
  float s=0.f;
  for(int c=0;c<1024;c++) s+=w[c]*gv[c];
  t6b[t]=s;
}

} // namespace

extern "C" void kernel_launch(void* const* d_in, const int* in_sizes, int n_in,
                              void* d_out, int out_size, void* d_ws, size_t ws_size,
                              hipStream_t stream){
  const float* x   =(const float*)d_in[0];
  const float* wa_1[4]={(const float*)d_in[1],(const float*)d_in[3],(const float*)d_in[5],(const float*)d_in[7]};
  const float* wa_2[4]={(const float*)d_in[2],(const float*)d_in[4],(const float*)d_in[6],(const float*)d_in[8]};
  const float* wfn[4]={(const float*)d_in[9],(const float*)d_in[10],(const float*)d_in[11],(const float*)d_in[12]};
  const float* wec[4]={(const float*)d_in[13],(const float*)d_in[14],(const float*)d_in[15],(const float*)d_in[16]};
  const float* w5=(const float*)d_in[17];
  const float* w6=(const float*)d_in[18];
  const float* w7=(const float*)d_in[19];
  const float* w8=(const float*)d_in[20];
  const float* gs[7]; const float* bs[7];
  for(int i=0;i<7;i++){ gs[i]=(const float*)d_in[21+2*i]; bs[i]=(const float*)d_in[22+2*i]; }

  const int Cs[4]={10,64,64,128};
  const int Co[4]={64,64,128,256};
  const size_t U=(size_t)BB*NP;
  const size_t NPNP=(size_t)NP*NP;

  float* base=(float*)d_ws;
  size_t off=0;
  auto alloc=[&](size_t nfl)->float*{ float* p=base+off; off+=(nfl+3)&~(size_t)3; return p; };

  float* f_buf = alloc(10*U);
  float* xcat  = alloc(512*U);
  float* sq    = alloc(U);
  int*   idxb  = (int*)alloc(20*U);
  float* xTb   = alloc(128*U);
  float* p1Tb  = alloc(128*U);
  float* a2Tb  = alloc(128*U);
  float* R2    = alloc(256*U);      // nbm then T3
  float* ymx   = alloc(256*U);
  float* ymn   = alloc(256*U);
  float* sums  = alloc(2048);
  float* sct   = alloc(4096);
  float* gvecb = alloc(4096);
  float* t6b   = alloc(2048);
  float* meanxb= alloc(16);
  // weight buffers
  float* wa12T[4]; float* wecAT[4]; float* wecBGT[4]; float* wfnT[4];
  for(int s=0;s<4;s++){
    int C=Cs[s], Cout=Co[s];
    wa12T[s]=alloc((size_t)C*2*C);
    wecAT[s]=alloc((size_t)C*Cout);
    wecBGT[s]=alloc((size_t)(C+512)*Cout);
    wfnT[s]=alloc((size_t)2*C*512);
  }
  float* w5T=alloc((size_t)512*1024); float* w6mT=alloc((size_t)128*512);
  float* w7T=alloc((size_t)512*256);  float* w8T=alloc((size_t)256*50);

  // R1: [0..512U) = Dbuf (per-batch) ; [512U..1024U) = gfb ; later y5 (full), y6, y7
  float* R1 = alloc(1024*U);
  float* Dbuf=R1;
  float* gfb=R1+512*U;
  float* y5=R1; float* y6=R1; float* y7=R1+512*U;
  float* nbm=R2; float* T3=R2;

  // optional 4-batch distance buffer
  int DZ=1; float* Dall=Dbuf;
  {
    size_t totalF = ws_size/sizeof(float);
    if(totalF > off && (totalF-off) >= (size_t)2048*U + 1024){
      Dall = alloc(2048*U); DZ=4;
    }
  }

  hipMemsetAsync(sums,0,2048*sizeof(float),stream);

  for(int s=0;s<4;s++){
    int C=Cs[s], Cout=Co[s], Cin=2*C+512;
    // wa12T: [C][2C], cols 0..C-1 = Wa1^T, cols C.. = Wa2^T
    k_transpose<<<(C*C+255)/256,256,0,stream>>>(wa_1[s],wa12T[s],C,C,C,0,2*C,0);
    k_transpose<<<(C*C+255)/256,256,0,stream>>>(wa_2[s],wa12T[s],C,C,C,0,2*C,C);
    k_transpose<<<(C*Cout+255)/256,256,0,stream>>>(wec[s],wecAT[s],Cout,C,Cin,0,Cout,0);
    // wecBGT rows 0..C-1 = WecB^T, rows C..C+511 = WecG^T
    k_transpose<<<(C*Cout+255)/256,256,0,stream>>>(wec[s],wecBGT[s],Cout,C,Cin,C,Cout,0);
    k_transpose<<<(512*Cout+255)/256,256,0,stream>>>(wec[s],wecBGT[s]+(size_t)C*Cout,Cout,512,Cin,2*C,Cout,0);
    k_transpose<<<(2*C*512+255)/256,256,0,stream>>>(wfn[s],wfnT[s],512,2*C,2*C,0,512,0);
  }
  k_transpose<<<(512*1024+255)/256,256,0,stream>>>(w5,w5T,1024,512,512,0,1024,0);
  k_transpose<<<(128*512+255)/256,256,0,stream>>>(w6,w6mT,512,128,1152,0,512,0);
  k_transpose<<<(512*256+255)/256,256,0,stream>>>(w7,w7T,256,512,512,0,256,0);
  k_transpose<<<(256*50+255)/256,256,0,stream>>>(w8,w8T,50,256,256,0,50,0);

  k_meanx<<<12,256,0,stream>>>(x,meanxb);
  k_repsurf<<<(BB*NP+255)/256,256,0,stream>>>(x,meanxb,f_buf);

  const float* xin[4]={f_buf, xcat, xcat+(size_t)64*NP, xcat+(size_t)128*NP};
  const size_t BSs[4]={(size_t)10*NP,(size_t)512*NP,(size_t)512*NP,(size_t)512*NP};
  float* xoutb[4]={xcat, xcat+(size_t)64*NP, xcat+(size_t)128*NP, xcat+(size_t)256*NP};

  for(int s=0;s<4;s++){
    int C=Cs[s], Cout=Co[s];
    size_t BS=BSs[s];
    k_sqnorm<<<(int)((U+255)/256),256,0,stream>>>(xin[s],BS,sq,C);
    if(DZ==4){
      k_dist<<<dim3(NP/128,NP/128,4),256,0,stream>>>(xin[s],BS,sq,Dall,NPNP,C);
      k_topk<<<dim3(NP/4,1,4),256,0,stream>>>(Dall,NPNP,idxb);
    } else {
      for(int b=0;b<BB;b++){
        k_dist<<<dim3(NP/128,NP/128,1),256,0,stream>>>(xin[s]+(size_t)b*BS,BS,sq+(size_t)b*NP,Dbuf,NPNP,C);
        k_topk<<<dim3(NP/4,1,1),256,0,stream>>>(Dbuf,NPNP,idxb+(size_t)b*NP*KK);
      }
    }
    k_nbmax<<<(int)((BB*(size_t)C*NP+255)/256),256,0,stream>>>(xin[s],BS,idxb,nbm,C);
    // gf = relu(Wfn @ [x; nbmax])
    k_g128<1,false><<<dim3(16,4,BB),256,0,stream>>>(wfnT[s],512,512,2*C, xin[s],BS,C, nbm,(size_t)C*NP,
                                                    nullptr,0, nullptr,0, gfb,(size_t)512*NP, NP);
    // T3 = [WecB|WecG] @ [x; gf]
    k_g64<0,false><<<dim3(32,Cout/64,BB),256,0,stream>>>(wecBGT[s],Cout,Cout,C+512, xin[s],BS,C, gfb,(size_t)512*NP,
                                                    nullptr,0, nullptr,0, T3,(size_t)Cout*NP, NP, nullptr,0);
    // P1^T and (Wa2 x)^T via transposed dual-write GEMM
    k_g64<5,false><<<dim3(32,(2*C+63)/64,BB),256,0,stream>>>(wa12T[s],2*C,2*C,C, xin[s],BS,C, nullptr,0,
                                                    nullptr,0, nullptr,0, p1Tb,0, NP, a2Tb,C);
    if(s==0) k_trT<<<dim3(NP/32,1,BB),256,0,stream>>>(f_buf,BSs[0],xTb,10);
    float* sb=sums+(size_t)s*512; float* qb=sb+256;
    if(s==0)      k_fused<10,64  ><<<dim3(NP/64,1,BB),256,0,stream>>>(xTb,p1Tb,a2Tb,idxb,wecAT[s],T3,ymx,ymn,sb,qb);
    else if(s==1) k_fused<64,64  ><<<dim3(NP/64,1,BB),256,0,stream>>>(xTb,p1Tb,a2Tb,idxb,wecAT[s],T3,ymx,ymn,sb,qb);
    else if(s==2) k_fused<64,128 ><<<dim3(NP/64,2,BB),256,0,stream>>>(xTb,p1Tb,a2Tb,idxb,wecAT[s],T3,ymx,ymn,sb,qb);
    else          k_fused<128,256><<<dim3(NP/64,4,BB),256,0,stream>>>(xTb,p1Tb,a2Tb,idxb,wecAT[s],T3,ymx,ymn,sb,qb);
    k_stageoutT<<<dim3(NP/32,Cout/32,BB),256,0,stream>>>(ymx,ymn,sb,qb,gs[s],bs[s],
                      1.f/(float)((size_t)BB*NP*KK), xoutb[s],(size_t)512*NP, xTb,Cout, s<3?1:0);
  }

  // head
  k_g128<0,false><<<dim3(16,8,BB),256,0,stream>>>(w5T,1024,1024,512, xcat,(size_t)512*NP,512, nullptr,0,
                                                  nullptr,0, nullptr,0, y5,(size_t)1024*NP, NP);
  k_stats<<<1024,256,0,stream>>>(y5,gs[4],bs[4],sct,1024);
  k_gvec<<<BB*1024,256,0,stream>>>(y5,sct,gvecb,1024,1024);
  k_t6<<<(BB*512+255)/256,256,0,stream>>>(gvecb,w6,t6b);
  k_g128<3,false><<<dim3(16,4,BB),256,0,stream>>>(w6mT,512,512,128, xcat+(size_t)128*NP,(size_t)512*NP,128,
                                                  nullptr,0, t6b,512, nullptr,0, y6,(size_t)512*NP, NP);
  k_stats<<<512,256,0,stream>>>(y6,gs[5],bs[5],sct,512);
  k_g64<0,true><<<dim3(32,4,BB),256,0,stream>>>(w7T,256,256,512, y6,(size_t)512*NP,512, nullptr,0,
                                                nullptr,0, sct,512, y7,(size_t)256*NP, NP, nullptr,0);
  k_stats<<<256,256,0,stream>>>(y7,gs[6],bs[6],sct,256);
  k_g64<1,true><<<dim3(32,1,BB),256,0,stream>>>(w8T,50,50,256, y7,(size_t)256*NP,256, nullptr,0,
                                                nullptr,0, sct,256, (float*)d_out,(size_t)50*NP, NP, nullptr,0);

  (void)in_sizes; (void)n_in; (void)out_size;
}